// Round 6
// baseline (511.972 us; speedup 1.0000x reference)
//
#include <hip/hip_runtime.h>
#include <cstdint>

#define D_MODEL 1024
#define D_INNER 2048
#define NSTATE  16
#define DT_RANK 64
#define SEQ     2048
#define NBATCH  2
#define NTOK    (NBATCH * SEQ)   // 4096

// chunked scan
#define NC      32               // chunks per sequence
#define CHK     64               // steps per chunk (NC*CHK == SEQ)
#define NGRP    8                // groups of 8 steps per chunk

// x_proj split-K
#define KS      8                // K slices of 256

typedef float  f32x4  __attribute__((ext_vector_type(4)));
typedef __bf16 bf16x8 __attribute__((ext_vector_type(8)));
typedef short  s16x8  __attribute__((ext_vector_type(8)));

__device__ __forceinline__ unsigned short f2bf(float f) {
  union { float f; uint32_t u; } a; a.f = f;
  uint32_t u = a.u;
  uint32_t r = (u + 0x7FFFu + ((u >> 16) & 1u)) >> 16;
  return (unsigned short)r;
}
__device__ __forceinline__ float bf2f(unsigned short h) {
  union { uint32_t u; float f; } a; a.u = ((uint32_t)h) << 16;
  return a.f;
}

__device__ __forceinline__ void gload16(const void* g, void* l) {
  __builtin_amdgcn_global_load_lds((__attribute__((address_space(1))) void*)g,
                                   (__attribute__((address_space(3))) void*)l,
                                   16, 0, 0);
}

// ---------------- RMSNorm + cast to bf16 ----------------
__global__ __launch_bounds__(256) void rmsnorm_kernel(const float* __restrict__ x,
                                                      const float* __restrict__ nw,
                                                      unsigned short* __restrict__ xn) {
  const int row = blockIdx.x;
  const float4 v = ((const float4*)(x + (size_t)row * D_MODEL))[threadIdx.x];
  float ss = v.x*v.x + v.y*v.y + v.z*v.z + v.w*v.w;
  #pragma unroll
  for (int m = 32; m; m >>= 1) ss += __shfl_xor(ss, m);
  __shared__ float red[4];
  if ((threadIdx.x & 63) == 0) red[threadIdx.x >> 6] = ss;
  __syncthreads();
  const float tot = red[0] + red[1] + red[2] + red[3];
  const float rs = rsqrtf(tot * (1.0f / D_MODEL) + 1e-5f);
  const float4 w = ((const float4*)nw)[threadIdx.x];
  ushort4 o;
  o.x = f2bf(v.x * rs * w.x);
  o.y = f2bf(v.y * rs * w.y);
  o.z = f2bf(v.z * rs * w.z);
  o.w = f2bf(v.w * rs * w.w);
  ((ushort4*)(xn + (size_t)row * D_MODEL))[threadIdx.x] = o;
}

// ---------------- transpose W[K][N] f32 -> Wt[Npad][K] bf16 (zero-pad rows N..Npad) ----
__global__ __launch_bounds__(256) void transpose_cast_kernel(const float* __restrict__ W,
                                                             unsigned short* __restrict__ Wt,
                                                             int K, int N, int Npad) {
  __shared__ float tile[32][33];
  const int tx = threadIdx.x & 31, ty = threadIdx.x >> 5;
  const int kt = blockIdx.y * 32, nt = blockIdx.x * 32;
  #pragma unroll
  for (int i = 0; i < 4; ++i) {
    const int k = kt + ty + i*8, n = nt + tx;
    tile[ty + i*8][tx] = (k < K && n < N) ? W[(size_t)k * N + n] : 0.0f;
  }
  __syncthreads();
  #pragma unroll
  for (int i = 0; i < 4; ++i) {
    const int n = nt + ty + i*8, k = kt + tx;
    if (n < Npad && k < K) Wt[(size_t)n * K + k] = f2bf(tile[tx][ty + i*8]);
  }
}

// ---------------- GEMM: C[M][N] = A[M][K] @ Bt[N][K]^T  (bf16 in, fp32 acc) ----------
// MODE 0: split -> xi_raw bf16 (col<2048), res bf16 (col>=2048). N=4096
// MODE 1: split-K partial (grid.z = kz, 256 K each) -> dP f32 [kz][M][128]
// MODE 2: softplus(v + dt_b[col]) -> delta bf16 [M][2048]. N=2048
// MODE 3: v + x[row][col] -> out f32 [M][1024]. N=1024
template<int MODE>
__global__ __launch_bounds__(256) void gemm_bt_kernel(const unsigned short* __restrict__ A,
                                                      const unsigned short* __restrict__ Bt,
                                                      const int M, const int N, const int K,
                                                      void* __restrict__ out0,
                                                      void* __restrict__ out1,
                                                      const float* __restrict__ extra) {
  __shared__ __align__(16) unsigned short sA[128 * 32];
  __shared__ __align__(16) unsigned short sB[128 * 32];
  const int tid = threadIdx.x;
  const int w = tid >> 6, lane = tid & 63;
  const int m0 = blockIdx.y * 128, n0 = blockIdx.x * 128;
  const int wm = w >> 1, wn = w & 1;
  const int lr = lane & 15, kq = lane >> 4;
  const int kz = (MODE == 1) ? blockIdx.z : 0;
  const int kbeg = (MODE == 1) ? kz * (2048 / KS) : 0;
  const int kend = (MODE == 1) ? kbeg + (2048 / KS) : K;

  f32x4 acc[4][4] = {};

  // staging: LDS chunk p=(row,qlds) holds global (row, qlds ^ (row&3))  [4-way-conflict swizzle]
  const int r0 = tid >> 2;
  const int qb = ((tid & 3) ^ (r0 & 3)) * 16;      // source byte-in-row (swizzle-inverse)
  const char* pA0 = (const char*)A + ((size_t)(m0 + r0)      * K) * 2 + qb;
  const char* pA1 = (const char*)A + ((size_t)(m0 + r0 + 64) * K) * 2 + qb;
  const char* pB0 = (const char*)Bt + ((size_t)(n0 + r0)      * K) * 2 + qb;
  const char* pB1 = (const char*)Bt + ((size_t)(n0 + r0 + 64) * K) * 2 + qb;
  char* ldsA0 = (char*)sA + w * 1024;
  char* ldsA1 = (char*)sA + 4096 + w * 1024;
  char* ldsB0 = (char*)sB + w * 1024;
  char* ldsB1 = (char*)sB + 4096 + w * 1024;

  // fragment read pointers (swizzled quarter)
  const int kqs = (kq ^ (lr & 3)) * 8;
  const unsigned short* pa = sA + (wm*64 + lr) * 32 + kqs;
  const unsigned short* pb = sB + (wn*64 + lr) * 32 + kqs;

  for (int k0 = kbeg; k0 < kend; k0 += 32) {
    __syncthreads();
    gload16(pA0 + (size_t)k0 * 2, ldsA0);
    gload16(pA1 + (size_t)k0 * 2, ldsA1);
    gload16(pB0 + (size_t)k0 * 2, ldsB0);
    gload16(pB1 + (size_t)k0 * 2, ldsB1);
    __syncthreads();
    bf16x8 af[4], bb[4];
    #pragma unroll
    for (int mf = 0; mf < 4; ++mf)
      af[mf] = __builtin_bit_cast(bf16x8, *(const s16x8*)(pa + mf * 16 * 32));
    #pragma unroll
    for (int nf = 0; nf < 4; ++nf)
      bb[nf] = __builtin_bit_cast(bf16x8, *(const s16x8*)(pb + nf * 16 * 32));
    #pragma unroll
    for (int mf = 0; mf < 4; ++mf)
      #pragma unroll
      for (int nf = 0; nf < 4; ++nf)
        acc[mf][nf] = __builtin_amdgcn_mfma_f32_16x16x32_bf16(af[mf], bb[nf], acc[mf][nf], 0, 0, 0);
  }

  #pragma unroll
  for (int mf = 0; mf < 4; ++mf) {
    #pragma unroll
    for (int nf = 0; nf < 4; ++nf) {
      #pragma unroll
      for (int r = 0; r < 4; ++r) {
        const int row = m0 + wm*64 + mf*16 + kq*4 + r;
        const int col = n0 + wn*64 + nf*16 + lr;
        const float v = acc[mf][nf][r];
        if constexpr (MODE == 0) {
          if (col < D_INNER) ((unsigned short*)out0)[(size_t)row * D_INNER + col] = f2bf(v);
          else               ((unsigned short*)out1)[(size_t)row * D_INNER + (col - D_INNER)] = f2bf(v);
        } else if constexpr (MODE == 1) {
          ((float*)out0)[((size_t)kz * NTOK + row) * 128 + col] = v;
        } else if constexpr (MODE == 2) {
          const float t = v + extra[col];
          const float sp = (t > 20.0f) ? t : log1pf(__expf(t));
          ((unsigned short*)out0)[(size_t)row * D_INNER + col] = f2bf(sp);
        } else {
          ((float*)out0)[(size_t)row * D_MODEL + col] = v + extra[(size_t)row * D_MODEL + col];
        }
      }
    }
  }
}

// ---------------- combine x_proj split-K partials -> dr bf16 [M][64], BC f32 [M][32] ----
__global__ __launch_bounds__(256) void xproj_combine_kernel(const float* __restrict__ dP,
                                                            unsigned short* __restrict__ dr,
                                                            float* __restrict__ BC) {
  const int t = blockIdx.x * 256 + threadIdx.x;
  const int row = t >> 7, col = t & 127;
  if (col >= DT_RANK + 2 * NSTATE) return;
  float s = 0.0f;
  #pragma unroll
  for (int kz = 0; kz < KS; ++kz)
    s += dP[((size_t)kz * NTOK + row) * 128 + col];
  if (col < DT_RANK) dr[(size_t)row * DT_RANK + col] = f2bf(s);
  else               BC[(size_t)row * 32 + (col - DT_RANK)] = s;
}

// ---------------- causal depthwise conv (width 4) + bias + SiLU, 8 ch/thread ------
__global__ __launch_bounds__(256) void conv_silu_kernel(const unsigned short* __restrict__ xi_raw,
                                                        const float* __restrict__ cw,
                                                        const float* __restrict__ cb,
                                                        unsigned short* __restrict__ xi) {
  const int t = blockIdx.x * 256 + threadIdx.x;   // NTOK*256 threads, 8 channels each
  const int d8 = (t & 255) * 8;
  const int row = t >> 8;                         // b*SEQ + l
  const int l = row & (SEQ - 1);

  float acc[8];
  #pragma unroll
  for (int c = 0; c < 8; c += 4) {
    const f32x4 bv = *(const f32x4*)(cb + d8 + c);
    acc[c+0] = bv[0]; acc[c+1] = bv[1]; acc[c+2] = bv[2]; acc[c+3] = bv[3];
  }
  // per-channel weight rows (4 taps each, 16B aligned)
  f32x4 wv[8];
  #pragma unroll
  for (int c = 0; c < 8; ++c) wv[c] = ((const f32x4*)cw)[d8 + c];

  #pragma unroll
  for (int tap = 0; tap < 4; ++tap) {
    const int lp = l - 3 + tap;
    if (lp >= 0) {
      const s16x8 v = *(const s16x8*)(xi_raw + (size_t)(row - 3 + tap) * D_INNER + d8);
      #pragma unroll
      for (int c = 0; c < 8; ++c)
        acc[c] += wv[c][tap] * bf2f((unsigned short)v[c]);
    }
  }
  s16x8 o;
  #pragma unroll
  for (int c = 0; c < 8; ++c) {
    const float a = acc[c] / (1.0f + __expf(-acc[c]));
    o[c] = (short)f2bf(a);
  }
  *(s16x8*)(xi + (size_t)row * D_INNER + d8) = o;
}

// ---------------- chunked selective scan ----------------
// PASS 0: per-chunk summary with s_in=0 -> aprod[16], send[16]  (layout [b][c][d][16] f32)
// PASS 1: replay chunk from initS, fused y = C.s + u*D, gate by silu(res), store yg bf16
// block = 256 threads = 256 channels; grid = NBATCH*NC*(D_INNER/256) = 512
template<int PASS>
__global__ __launch_bounds__(256) void scan_pass_kernel(const unsigned short* __restrict__ delta,
                                                        const unsigned short* __restrict__ xi,
                                                        const unsigned short* __restrict__ res,
                                                        const float* __restrict__ BC,
                                                        const float* __restrict__ A_log,
                                                        const float* __restrict__ Dv,
                                                        const float* __restrict__ initS,
                                                        float* __restrict__ aprodOut,
                                                        float* __restrict__ sendOut,
                                                        unsigned short* __restrict__ yg) {
  const int tid = threadIdx.x;
  const int db = blockIdx.x & 7;
  const int c  = (blockIdx.x >> 3) & (NC - 1);
  const int b  = blockIdx.x >> 8;
  const int d  = db * 256 + tid;
  const int row0 = b * SEQ + c * CHK;
  const size_t ob = ((size_t)(b * NC + c) * D_INNER + d) * 16;

  float Ac[16];
  #pragma unroll
  for (int q = 0; q < 4; ++q) {
    f32x4 t = ((const f32x4*)(A_log + (size_t)d * 16))[q];
    Ac[q*4+0] = -expf(t[0]); Ac[q*4+1] = -expf(t[1]);
    Ac[q*4+2] = -expf(t[2]); Ac[q*4+3] = -expf(t[3]);
  }
  float s[16];
  float ap[16];
  if constexpr (PASS == 0) {
    #pragma unroll
    for (int n = 0; n < 16; ++n) { s[n] = 0.0f; ap[n] = 1.0f; }
  } else {
    #pragma unroll
    for (int q = 0; q < 4; ++q)
      ((f32x4*)s)[q] = ((const f32x4*)(initS + ob))[q];
  }
  float Dd = 0.0f;
  if constexpr (PASS == 1) Dd = Dv[d];

  __shared__ float bcbuf[2][8][32];
  // stage BC rows for group g into parity p
  auto stageg = [&](int g, int p) {
    bcbuf[p][tid >> 5][tid & 31] = BC[(size_t)(row0 + g * 8) * 32 + tid];
  };
  stageg(0, 0);

  for (int g = 0; g < NGRP; ++g) {
    // register-prefetch this group's per-channel inputs (independent of state)
    unsigned short dl[8], uu[8], rr[8];
    #pragma unroll
    for (int j = 0; j < 8; ++j) {
      const size_t row = (size_t)(row0 + g * 8 + j) * D_INNER + d;
      dl[j] = delta[row];
      uu[j] = xi[row];
      if constexpr (PASS == 1) rr[j] = res[row];
    }
    __syncthreads();
    if (g + 1 < NGRP) stageg(g + 1, (g + 1) & 1);

    #pragma unroll
    for (int j = 0; j < 8; ++j) {
      const float dlt = bf2f(dl[j]);
      const float u   = bf2f(uu[j]);
      const float dlu = dlt * u;
      float bc[32];
      #pragma unroll
      for (int q = 0; q < (PASS ? 8 : 4); ++q)
        ((f32x4*)bc)[q] = ((const f32x4*)(&bcbuf[g & 1][j][0]))[q];
      #pragma unroll
      for (int n = 0; n < 16; ++n) {
        const float dA = __expf(dlt * Ac[n]);
        s[n] = dA * s[n] + dlu * bc[n];
        if constexpr (PASS == 0) ap[n] *= dA;
      }
      if constexpr (PASS == 1) {
        float y = 0.0f;
        #pragma unroll
        for (int n = 0; n < 16; ++n) y += s[n] * bc[16 + n];
        const float r = bf2f(rr[j]);
        const float o = (y + u * Dd) * (r / (1.0f + __expf(-r)));
        yg[(size_t)(row0 + g * 8 + j) * D_INNER + d] = f2bf(o);
      }
    }
  }

  if constexpr (PASS == 0) {
    #pragma unroll
    for (int q = 0; q < 4; ++q) {
      ((f32x4*)(aprodOut + ob))[q] = ((f32x4*)ap)[q];
      ((f32x4*)(sendOut + ob))[q]  = ((f32x4*)s)[q];
    }
  }
}

// ---------------- combine chunk summaries: carry_c = state entering chunk c ----------
// float4-per-thread over [b][d][n]; 2*32768/4 = 16384 threads
__global__ __launch_bounds__(256) void scan_combine_kernel(const float* __restrict__ aprod,
                                                           const float* __restrict__ send,
                                                           float* __restrict__ initS) {
  const int t = blockIdx.x * 256 + threadIdx.x;
  const int b = t >> 13;
  const int rq = t & 8191;
  f32x4 carry = {0.0f, 0.0f, 0.0f, 0.0f};
  #pragma unroll
  for (int c = 0; c < NC; ++c) {
    const size_t idx = (size_t)(b * NC + c) * 8192 + rq;
    ((f32x4*)initS)[idx] = carry;
    const f32x4 a = ((const f32x4*)aprod)[idx];
    const f32x4 e = ((const f32x4*)send)[idx];
    carry = a * carry + e;
  }
}

// ---------------- launcher ----------------
extern "C" void kernel_launch(void* const* d_in, const int* in_sizes, int n_in,
                              void* d_out, int out_size, void* d_ws, size_t ws_size,
                              hipStream_t stream) {
  const float* x        = (const float*)d_in[0];
  const float* in_proj  = (const float*)d_in[1];
  const float* conv_w   = (const float*)d_in[2];
  const float* conv_b   = (const float*)d_in[3];
  const float* x_proj   = (const float*)d_in[4];
  const float* dt_proj  = (const float*)d_in[5];
  const float* dt_b     = (const float*)d_in[6];
  const float* A_log    = (const float*)d_in[7];
  const float* Dv       = (const float*)d_in[8];
  const float* out_proj = (const float*)d_in[9];
  const float* norm_w   = (const float*)d_in[10];

  char* ws = (char*)d_ws;
  size_t off = 0;
  auto alloc = [&](size_t bytes) {
    char* p = ws + off; off += (bytes + 255) & ~(size_t)255; return p;
  };
  unsigned short* xn     = (unsigned short*)alloc((size_t)NTOK * D_MODEL * 2);   // 8 MB (reused as initS)
  unsigned short* W1t    = (unsigned short*)alloc((size_t)(2 * D_INNER) * D_MODEL * 2);
  unsigned short* xi_raw = (unsigned short*)alloc((size_t)NTOK * D_INNER * 2);   // 16 MB (reused: dP, then aprod+send)
  unsigned short* resb   = (unsigned short*)alloc((size_t)NTOK * D_INNER * 2);
  unsigned short* xi     = (unsigned short*)alloc((size_t)NTOK * D_INNER * 2);
  unsigned short* W2t    = (unsigned short*)alloc((size_t)128 * D_INNER * 2);
  unsigned short* dr     = (unsigned short*)alloc((size_t)NTOK * DT_RANK * 2);
  float*          BC     = (float*)alloc((size_t)NTOK * 32 * 4);
  unsigned short* W3t    = (unsigned short*)alloc((size_t)D_INNER * DT_RANK * 2);
  unsigned short* dlt    = (unsigned short*)alloc((size_t)NTOK * D_INNER * 2);
  unsigned short* ygb    = (unsigned short*)alloc((size_t)NTOK * D_INNER * 2);
  unsigned short* W4t    = (unsigned short*)alloc((size_t)D_MODEL * D_INNER * 2);

  // scratch reuse (dead-buffer overlays):
  //   dP (16.77 MB, x_proj split-K partials) overlays xi_raw — dead between conv and scan
  //   aprod/send (8 MB each) overlay xi_raw — after xproj_combine
  //   initS (8 MB) overlays xn — dead after GEMM1
  float* dP    = (float*)xi_raw;
  float* aprod = (float*)xi_raw;
  float* send  = (float*)((char*)xi_raw + 8388608);
  float* initS = (float*)xn;

  rmsnorm_kernel<<<NTOK, 256, 0, stream>>>(x, norm_w, xn);
  transpose_cast_kernel<<<dim3(4096/32, 1024/32), 256, 0, stream>>>(in_proj, W1t, 1024, 4096, 4096);
  transpose_cast_kernel<<<dim3(128/32, 2048/32), 256, 0, stream>>>(x_proj, W2t, 2048, 96, 128);
  transpose_cast_kernel<<<dim3(2048/32, 64/32), 256, 0, stream>>>(dt_proj, W3t, 64, 2048, 2048);
  transpose_cast_kernel<<<dim3(1024/32, 2048/32), 256, 0, stream>>>(out_proj, W4t, 2048, 1024, 1024);

  gemm_bt_kernel<0><<<dim3(4096/128, 4096/128), 256, 0, stream>>>(xn, W1t, NTOK, 4096, 1024, xi_raw, resb, nullptr);
  conv_silu_kernel<<<NTOK, 256, 0, stream>>>(xi_raw, conv_w, conv_b, xi);
  gemm_bt_kernel<1><<<dim3(1, 4096/128, KS), 256, 0, stream>>>(xi, W2t, NTOK, 128, 2048, dP, nullptr, nullptr);
  xproj_combine_kernel<<<(NTOK * 128) / 256, 256, 0, stream>>>(dP, dr, BC);
  gemm_bt_kernel<2><<<dim3(2048/128, 4096/128), 256, 0, stream>>>(dr, W3t, NTOK, 2048, 64, dlt, nullptr, dt_b);

  scan_pass_kernel<0><<<NBATCH * NC * (D_INNER/256), 256, 0, stream>>>(
      dlt, xi, nullptr, BC, A_log, nullptr, nullptr, aprod, send, nullptr);
  scan_combine_kernel<<<64, 256, 0, stream>>>(aprod, send, initS);
  scan_pass_kernel<1><<<NBATCH * NC * (D_INNER/256), 256, 0, stream>>>(
      dlt, xi, resb, BC, A_log, Dv, initS, nullptr, nullptr, ygb);

  gemm_bt_kernel<3><<<dim3(1024/128, 4096/128), 256, 0, stream>>>(ygb, W4t, NTOK, 1024, 2048, d_out, nullptr, x);
}

// Round 7
// 378.531 us; speedup vs baseline: 1.3525x; 1.3525x over previous
//
#include <hip/hip_runtime.h>
#include <cstdint>

#define D_MODEL 1024
#define D_INNER 2048
#define NSTATE  16
#define DT_RANK 64
#define SEQ     2048
#define NBATCH  2
#define NTOK    (NBATCH * SEQ)   // 4096

// chunked scan
#define NC      32               // chunks per sequence
#define CHK     64               // steps per chunk (NC*CHK == SEQ)
#define NGRP    8                // groups of 8 steps per chunk

typedef float  f32x4  __attribute__((ext_vector_type(4)));
typedef __bf16 bf16x8 __attribute__((ext_vector_type(8)));
typedef short  s16x8  __attribute__((ext_vector_type(8)));

__device__ __forceinline__ unsigned short f2bf(float f) {
  union { float f; uint32_t u; } a; a.f = f;
  uint32_t u = a.u;
  uint32_t r = (u + 0x7FFFu + ((u >> 16) & 1u)) >> 16;
  return (unsigned short)r;
}
__device__ __forceinline__ float bf2f(unsigned short h) {
  union { uint32_t u; float f; } a; a.u = ((uint32_t)h) << 16;
  return a.f;
}

__device__ __forceinline__ void gload16(const void* g, void* l) {
  __builtin_amdgcn_global_load_lds((__attribute__((address_space(1))) void*)g,
                                   (__attribute__((address_space(3))) void*)l,
                                   16, 0, 0);
}

// ---------------- RMSNorm + cast to bf16 ----------------
__global__ __launch_bounds__(256) void rmsnorm_kernel(const float* __restrict__ x,
                                                      const float* __restrict__ nw,
                                                      unsigned short* __restrict__ xn) {
  const int row = blockIdx.x;
  const float4 v = ((const float4*)(x + (size_t)row * D_MODEL))[threadIdx.x];
  float ss = v.x*v.x + v.y*v.y + v.z*v.z + v.w*v.w;
  #pragma unroll
  for (int m = 32; m; m >>= 1) ss += __shfl_xor(ss, m);
  __shared__ float red[4];
  if ((threadIdx.x & 63) == 0) red[threadIdx.x >> 6] = ss;
  __syncthreads();
  const float tot = red[0] + red[1] + red[2] + red[3];
  const float rs = rsqrtf(tot * (1.0f / D_MODEL) + 1e-5f);
  const float4 w = ((const float4*)nw)[threadIdx.x];
  ushort4 o;
  o.x = f2bf(v.x * rs * w.x);
  o.y = f2bf(v.y * rs * w.y);
  o.z = f2bf(v.z * rs * w.z);
  o.w = f2bf(v.w * rs * w.w);
  ((ushort4*)(xn + (size_t)row * D_MODEL))[threadIdx.x] = o;
}

// ---------------- transpose W[K][N] f32 -> Wt[Npad][K] bf16 (zero-pad rows N..Npad) ----
__global__ __launch_bounds__(256) void transpose_cast_kernel(const float* __restrict__ W,
                                                             unsigned short* __restrict__ Wt,
                                                             int K, int N, int Npad) {
  __shared__ float tile[32][33];
  const int tx = threadIdx.x & 31, ty = threadIdx.x >> 5;
  const int kt = blockIdx.y * 32, nt = blockIdx.x * 32;
  #pragma unroll
  for (int i = 0; i < 4; ++i) {
    const int k = kt + ty + i*8, n = nt + tx;
    tile[ty + i*8][tx] = (k < K && n < N) ? W[(size_t)k * N + n] : 0.0f;
  }
  __syncthreads();
  #pragma unroll
  for (int i = 0; i < 4; ++i) {
    const int n = nt + ty + i*8, k = kt + tx;
    if (n < Npad && k < K) Wt[(size_t)n * K + k] = f2bf(tile[tx][ty + i*8]);
  }
}

// ---------------- GEMM body: C[M][N] = A[M][K] @ Bt[N][K]^T  (bf16 in, fp32 acc) ------
// MODE 0: split -> xi_raw bf16 (col<2048), res bf16 (col>=2048). N=4096
// MODE 1: col<64 -> dr bf16 [M][64]; 64<=col<96 -> BC f32 [M][32]; else skip. N=128(pad)
// MODE 2: fast-softplus(v + dt_b[col]) -> delta bf16 [M][2048]. N=2048
// MODE 3: v + x[row][col] -> out f32 [M][1024]. N=1024
template<int MODE>
__device__ __forceinline__ void gemm_body(const unsigned short* __restrict__ A,
                                          const unsigned short* __restrict__ Bt,
                                          const int M, const int N, const int K,
                                          void* __restrict__ out0,
                                          void* __restrict__ out1,
                                          const float* __restrict__ extra) {
  __shared__ __align__(16) unsigned short sA[128 * 32];
  __shared__ __align__(16) unsigned short sB[128 * 32];
  const int tid = threadIdx.x;
  const int w = tid >> 6, lane = tid & 63;
  const int m0 = blockIdx.y * 128, n0 = blockIdx.x * 128;
  const int wm = w >> 1, wn = w & 1;
  const int lr = lane & 15, kq = lane >> 4;

  f32x4 acc[4][4] = {};

  // staging: LDS chunk p=(row,qlds) holds global (row, qlds ^ (row&3))  [4-way-conflict swizzle]
  const int r0 = tid >> 2;
  const int qb = ((tid & 3) ^ (r0 & 3)) * 16;      // source byte-in-row (swizzle-inverse)
  const char* pA0 = (const char*)A + ((size_t)(m0 + r0)      * K) * 2 + qb;
  const char* pA1 = (const char*)A + ((size_t)(m0 + r0 + 64) * K) * 2 + qb;
  const char* pB0 = (const char*)Bt + ((size_t)(n0 + r0)      * K) * 2 + qb;
  const char* pB1 = (const char*)Bt + ((size_t)(n0 + r0 + 64) * K) * 2 + qb;
  char* ldsA0 = (char*)sA + w * 1024;
  char* ldsA1 = (char*)sA + 4096 + w * 1024;
  char* ldsB0 = (char*)sB + w * 1024;
  char* ldsB1 = (char*)sB + 4096 + w * 1024;

  // fragment read pointers (swizzled quarter)
  const int kqs = (kq ^ (lr & 3)) * 8;
  const unsigned short* pa = sA + (wm*64 + lr) * 32 + kqs;
  const unsigned short* pb = sB + (wn*64 + lr) * 32 + kqs;

  for (int k0 = 0; k0 < K; k0 += 32) {
    __syncthreads();
    gload16(pA0 + (size_t)k0 * 2, ldsA0);
    gload16(pA1 + (size_t)k0 * 2, ldsA1);
    gload16(pB0 + (size_t)k0 * 2, ldsB0);
    gload16(pB1 + (size_t)k0 * 2, ldsB1);
    __syncthreads();
    bf16x8 af[4], bb[4];
    #pragma unroll
    for (int mf = 0; mf < 4; ++mf)
      af[mf] = __builtin_bit_cast(bf16x8, *(const s16x8*)(pa + mf * 16 * 32));
    #pragma unroll
    for (int nf = 0; nf < 4; ++nf)
      bb[nf] = __builtin_bit_cast(bf16x8, *(const s16x8*)(pb + nf * 16 * 32));
    #pragma unroll
    for (int mf = 0; mf < 4; ++mf)
      #pragma unroll
      for (int nf = 0; nf < 4; ++nf)
        acc[mf][nf] = __builtin_amdgcn_mfma_f32_16x16x32_bf16(af[mf], bb[nf], acc[mf][nf], 0, 0, 0);
  }

  #pragma unroll
  for (int mf = 0; mf < 4; ++mf) {
    #pragma unroll
    for (int nf = 0; nf < 4; ++nf) {
      #pragma unroll
      for (int r = 0; r < 4; ++r) {
        const int row = m0 + wm*64 + mf*16 + kq*4 + r;
        const int col = n0 + wn*64 + nf*16 + lr;
        const float v = acc[mf][nf][r];
        if constexpr (MODE == 0) {
          if (col < D_INNER) ((unsigned short*)out0)[(size_t)row * D_INNER + col] = f2bf(v);
          else               ((unsigned short*)out1)[(size_t)row * D_INNER + (col - D_INNER)] = f2bf(v);
        } else if constexpr (MODE == 1) {
          if (col < DT_RANK) ((unsigned short*)out0)[(size_t)row * DT_RANK + col] = f2bf(v);
          else if (col < DT_RANK + 2*NSTATE) ((float*)out1)[(size_t)row * (2*NSTATE) + (col - DT_RANK)] = v;
        } else if constexpr (MODE == 2) {
          // fast softplus: bf16 output makes libdevice log1pf precision wasted
          const float t = v + extra[col];
          const float sp = (t > 30.0f) ? t : __logf(1.0f + __expf(t));
          ((unsigned short*)out0)[(size_t)row * D_INNER + col] = f2bf(sp);
        } else {
          ((float*)out0)[(size_t)row * D_MODEL + col] = v + extra[(size_t)row * D_MODEL + col];
        }
      }
    }
  }
}

// distinct names so rocprof top-5 discriminates the four GEMMs
__global__ __launch_bounds__(256) void g0_inproj_kernel(const unsigned short* A, const unsigned short* Bt,
                                                        int M, int N, int K, void* o0, void* o1, const float* ex) {
  gemm_body<0>(A, Bt, M, N, K, o0, o1, ex);
}
__global__ __launch_bounds__(256) void g1_xproj_kernel(const unsigned short* A, const unsigned short* Bt,
                                                       int M, int N, int K, void* o0, void* o1, const float* ex) {
  gemm_body<1>(A, Bt, M, N, K, o0, o1, ex);
}
__global__ __launch_bounds__(256) void g2_dtproj_kernel(const unsigned short* A, const unsigned short* Bt,
                                                        int M, int N, int K, void* o0, void* o1, const float* ex) {
  gemm_body<2>(A, Bt, M, N, K, o0, o1, ex);
}
__global__ __launch_bounds__(256) void g3_outproj_kernel(const unsigned short* A, const unsigned short* Bt,
                                                         int M, int N, int K, void* o0, void* o1, const float* ex) {
  gemm_body<3>(A, Bt, M, N, K, o0, o1, ex);
}

// ---------------- causal depthwise conv (width 4) + bias + SiLU, 8 ch/thread ------
__global__ __launch_bounds__(256) void conv_silu_kernel(const unsigned short* __restrict__ xi_raw,
                                                        const float* __restrict__ cw,
                                                        const float* __restrict__ cb,
                                                        unsigned short* __restrict__ xi) {
  const int t = blockIdx.x * 256 + threadIdx.x;   // NTOK*256 threads, 8 channels each
  const int d8 = (t & 255) * 8;
  const int row = t >> 8;                         // b*SEQ + l
  const int l = row & (SEQ - 1);

  float acc[8];
  #pragma unroll
  for (int c = 0; c < 8; c += 4) {
    const f32x4 bv = *(const f32x4*)(cb + d8 + c);
    acc[c+0] = bv[0]; acc[c+1] = bv[1]; acc[c+2] = bv[2]; acc[c+3] = bv[3];
  }
  f32x4 wv[8];
  #pragma unroll
  for (int c = 0; c < 8; ++c) wv[c] = ((const f32x4*)cw)[d8 + c];

  #pragma unroll
  for (int tap = 0; tap < 4; ++tap) {
    const int lp = l - 3 + tap;
    if (lp >= 0) {
      const s16x8 v = *(const s16x8*)(xi_raw + (size_t)(row - 3 + tap) * D_INNER + d8);
      #pragma unroll
      for (int c = 0; c < 8; ++c)
        acc[c] += wv[c][tap] * bf2f((unsigned short)v[c]);
    }
  }
  s16x8 o;
  #pragma unroll
  for (int c = 0; c < 8; ++c) {
    const float a = acc[c] / (1.0f + __expf(-acc[c]));
    o[c] = (short)f2bf(a);
  }
  *(s16x8*)(xi + (size_t)row * D_INNER + d8) = o;
}

// ---------------- chunked selective scan ----------------
// PASS 0: per-chunk summary with s_in=0 -> aprod[16], send[16]  (layout [b][c][d][16] f32)
// PASS 1: replay chunk from initS, fused y = C.s + u*D, gate by silu(res), store yg bf16
// block = 256 threads = 256 channels; grid = NBATCH*NC*(D_INNER/256) = 512
template<int PASS>
__global__ __launch_bounds__(256) void scan_pass_kernel(const unsigned short* __restrict__ delta,
                                                        const unsigned short* __restrict__ xi,
                                                        const unsigned short* __restrict__ res,
                                                        const float* __restrict__ BC,
                                                        const float* __restrict__ A_log,
                                                        const float* __restrict__ Dv,
                                                        const float* __restrict__ initS,
                                                        float* __restrict__ aprodOut,
                                                        float* __restrict__ sendOut,
                                                        unsigned short* __restrict__ yg) {
  const int tid = threadIdx.x;
  const int db = blockIdx.x & 7;
  const int c  = (blockIdx.x >> 3) & (NC - 1);
  const int b  = blockIdx.x >> 8;
  const int d  = db * 256 + tid;
  const int row0 = b * SEQ + c * CHK;
  const size_t ob = ((size_t)(b * NC + c) * D_INNER + d) * 16;

  float Ac[16];
  #pragma unroll
  for (int q = 0; q < 4; ++q) {
    f32x4 t = ((const f32x4*)(A_log + (size_t)d * 16))[q];
    Ac[q*4+0] = -expf(t[0]); Ac[q*4+1] = -expf(t[1]);
    Ac[q*4+2] = -expf(t[2]); Ac[q*4+3] = -expf(t[3]);
  }
  float s[16];
  float ap[16];
  if constexpr (PASS == 0) {
    #pragma unroll
    for (int n = 0; n < 16; ++n) { s[n] = 0.0f; ap[n] = 1.0f; }
  } else {
    #pragma unroll
    for (int q = 0; q < 4; ++q)
      ((f32x4*)s)[q] = ((const f32x4*)(initS + ob))[q];
  }
  float Dd = 0.0f;
  if constexpr (PASS == 1) Dd = Dv[d];

  __shared__ float bcbuf[2][8][32];
  auto stageg = [&](int g, int p) {
    bcbuf[p][tid >> 5][tid & 31] = BC[(size_t)(row0 + g * 8) * 32 + tid];
  };
  stageg(0, 0);

  for (int g = 0; g < NGRP; ++g) {
    unsigned short dl[8], uu[8], rr[8];
    #pragma unroll
    for (int j = 0; j < 8; ++j) {
      const size_t row = (size_t)(row0 + g * 8 + j) * D_INNER + d;
      dl[j] = delta[row];
      uu[j] = xi[row];
      if constexpr (PASS == 1) rr[j] = res[row];
    }
    __syncthreads();
    if (g + 1 < NGRP) stageg(g + 1, (g + 1) & 1);

    #pragma unroll
    for (int j = 0; j < 8; ++j) {
      const float dlt = bf2f(dl[j]);
      const float u   = bf2f(uu[j]);
      const float dlu = dlt * u;
      float bc[32];
      #pragma unroll
      for (int q = 0; q < (PASS ? 8 : 4); ++q)
        ((f32x4*)bc)[q] = ((const f32x4*)(&bcbuf[g & 1][j][0]))[q];
      #pragma unroll
      for (int n = 0; n < 16; ++n) {
        const float dA = __expf(dlt * Ac[n]);
        s[n] = dA * s[n] + dlu * bc[n];
        if constexpr (PASS == 0) ap[n] *= dA;
      }
      if constexpr (PASS == 1) {
        float y = 0.0f;
        #pragma unroll
        for (int n = 0; n < 16; ++n) y += s[n] * bc[16 + n];
        const float r = bf2f(rr[j]);
        const float o = (y + u * Dd) * (r / (1.0f + __expf(-r)));
        yg[(size_t)(row0 + g * 8 + j) * D_INNER + d] = f2bf(o);
      }
    }
  }

  if constexpr (PASS == 0) {
    #pragma unroll
    for (int q = 0; q < 4; ++q) {
      ((f32x4*)(aprodOut + ob))[q] = ((f32x4*)ap)[q];
      ((f32x4*)(sendOut + ob))[q]  = ((f32x4*)s)[q];
    }
  }
}

// ---------------- combine chunk summaries: carry_c = state entering chunk c ----------
__global__ __launch_bounds__(256) void scan_combine_kernel(const float* __restrict__ aprod,
                                                           const float* __restrict__ send,
                                                           float* __restrict__ initS) {
  const int t = blockIdx.x * 256 + threadIdx.x;
  const int b = t >> 13;
  const int rq = t & 8191;
  f32x4 carry = {0.0f, 0.0f, 0.0f, 0.0f};
  #pragma unroll
  for (int c = 0; c < NC; ++c) {
    const size_t idx = (size_t)(b * NC + c) * 8192 + rq;
    ((f32x4*)initS)[idx] = carry;
    const f32x4 a = ((const f32x4*)aprod)[idx];
    const f32x4 e = ((const f32x4*)send)[idx];
    carry = a * carry + e;
  }
}

// ---------------- launcher ----------------
extern "C" void kernel_launch(void* const* d_in, const int* in_sizes, int n_in,
                              void* d_out, int out_size, void* d_ws, size_t ws_size,
                              hipStream_t stream) {
  const float* x        = (const float*)d_in[0];
  const float* in_proj  = (const float*)d_in[1];
  const float* conv_w   = (const float*)d_in[2];
  const float* conv_b   = (const float*)d_in[3];
  const float* x_proj   = (const float*)d_in[4];
  const float* dt_proj  = (const float*)d_in[5];
  const float* dt_b     = (const float*)d_in[6];
  const float* A_log    = (const float*)d_in[7];
  const float* Dv       = (const float*)d_in[8];
  const float* out_proj = (const float*)d_in[9];
  const float* norm_w   = (const float*)d_in[10];

  char* ws = (char*)d_ws;
  size_t off = 0;
  auto alloc = [&](size_t bytes) {
    char* p = ws + off; off += (bytes + 255) & ~(size_t)255; return p;
  };
  unsigned short* xn     = (unsigned short*)alloc((size_t)NTOK * D_MODEL * 2);   // 8 MB (reused as initS)
  unsigned short* W1t    = (unsigned short*)alloc((size_t)(2 * D_INNER) * D_MODEL * 2);
  unsigned short* xi_raw = (unsigned short*)alloc((size_t)NTOK * D_INNER * 2);   // 16 MB (reused: aprod+send)
  unsigned short* resb   = (unsigned short*)alloc((size_t)NTOK * D_INNER * 2);
  unsigned short* xi     = (unsigned short*)alloc((size_t)NTOK * D_INNER * 2);
  unsigned short* W2t    = (unsigned short*)alloc((size_t)128 * D_INNER * 2);
  unsigned short* dr     = (unsigned short*)alloc((size_t)NTOK * DT_RANK * 2);
  float*          BC     = (float*)alloc((size_t)NTOK * 32 * 4);
  unsigned short* W3t    = (unsigned short*)alloc((size_t)D_INNER * DT_RANK * 2);
  unsigned short* dlt    = (unsigned short*)alloc((size_t)NTOK * D_INNER * 2);
  unsigned short* ygb    = (unsigned short*)alloc((size_t)NTOK * D_INNER * 2);
  unsigned short* W4t    = (unsigned short*)alloc((size_t)D_MODEL * D_INNER * 2);

  // scratch reuse (dead-buffer overlays):
  //   aprod/send (8 MB each) overlay xi_raw (dead after conv)
  //   initS (8 MB) overlays xn (dead after GEMM1)
  float* aprod = (float*)xi_raw;
  float* send  = (float*)((char*)xi_raw + 8388608);
  float* initS = (float*)xn;

  rmsnorm_kernel<<<NTOK, 256, 0, stream>>>(x, norm_w, xn);
  transpose_cast_kernel<<<dim3(4096/32, 1024/32), 256, 0, stream>>>(in_proj, W1t, 1024, 4096, 4096);
  transpose_cast_kernel<<<dim3(128/32, 2048/32), 256, 0, stream>>>(x_proj, W2t, 2048, 96, 128);
  transpose_cast_kernel<<<dim3(2048/32, 64/32), 256, 0, stream>>>(dt_proj, W3t, 64, 2048, 2048);
  transpose_cast_kernel<<<dim3(1024/32, 2048/32), 256, 0, stream>>>(out_proj, W4t, 2048, 1024, 1024);

  g0_inproj_kernel<<<dim3(4096/128, 4096/128), 256, 0, stream>>>(xn, W1t, NTOK, 4096, 1024, xi_raw, resb, nullptr);
  conv_silu_kernel<<<NTOK, 256, 0, stream>>>(xi_raw, conv_w, conv_b, xi);
  g1_xproj_kernel<<<dim3(1, 4096/128), 256, 0, stream>>>(xi, W2t, NTOK, 128, 2048, dr, BC, nullptr);
  g2_dtproj_kernel<<<dim3(2048/128, 4096/128), 256, 0, stream>>>(dr, W3t, NTOK, 2048, 64, dlt, nullptr, dt_b);

  scan_pass_kernel<0><<<NBATCH * NC * (D_INNER/256), 256, 0, stream>>>(
      dlt, xi, nullptr, BC, A_log, nullptr, nullptr, aprod, send, nullptr);
  scan_combine_kernel<<<64, 256, 0, stream>>>(aprod, send, initS);
  scan_pass_kernel<1><<<NBATCH * NC * (D_INNER/256), 256, 0, stream>>>(
      dlt, xi, resb, BC, A_log, Dv, initS, nullptr, nullptr, ygb);

  g3_outproj_kernel<<<dim3(1024/128, 4096/128), 256, 0, stream>>>(ygb, W4t, NTOK, 1024, 2048, d_out, nullptr, x);
}

// Round 8
// 369.088 us; speedup vs baseline: 1.3871x; 1.0256x over previous
//
#include <hip/hip_runtime.h>
#include <cstdint>

#define D_MODEL 1024
#define D_INNER 2048
#define NSTATE  16
#define DT_RANK 64
#define SEQ     2048
#define NBATCH  2
#define NTOK    (NBATCH * SEQ)   // 4096

// chunked scan
#define NC      32               // chunks per sequence
#define CHK     64               // steps per chunk (NC*CHK == SEQ)
#define NGRP    8                // groups of 8 steps per chunk

typedef float  f32x4  __attribute__((ext_vector_type(4)));
typedef __bf16 bf16x8 __attribute__((ext_vector_type(8)));
typedef short  s16x8  __attribute__((ext_vector_type(8)));

__device__ __forceinline__ unsigned short f2bf(float f) {
  union { float f; uint32_t u; } a; a.f = f;
  uint32_t u = a.u;
  uint32_t r = (u + 0x7FFFu + ((u >> 16) & 1u)) >> 16;
  return (unsigned short)r;
}
__device__ __forceinline__ float bf2f(unsigned short h) {
  union { uint32_t u; float f; } a; a.u = ((uint32_t)h) << 16;
  return a.f;
}

__device__ __forceinline__ void gload16(const void* g, void* l) {
  __builtin_amdgcn_global_load_lds((__attribute__((address_space(1))) void*)g,
                                   (__attribute__((address_space(3))) void*)l,
                                   16, 0, 0);
}

// ---------------- fused prep: rmsnorm + 4 weight transposes, one launch ----------
// block ranges: [0,4096) rmsnorm | [4096,8192) W1 | [8192,8448) W2 | [8448,8576) W3 | [8576,10624) W4
__device__ __forceinline__ void rms_body(const float* __restrict__ x, const float* __restrict__ nw,
                                         unsigned short* __restrict__ xn, int row, float* red) {
  const float4 v = ((const float4*)(x + (size_t)row * D_MODEL))[threadIdx.x];
  float ss = v.x*v.x + v.y*v.y + v.z*v.z + v.w*v.w;
  #pragma unroll
  for (int m = 32; m; m >>= 1) ss += __shfl_xor(ss, m);
  if ((threadIdx.x & 63) == 0) red[threadIdx.x >> 6] = ss;
  __syncthreads();
  const float tot = red[0] + red[1] + red[2] + red[3];
  const float rs = rsqrtf(tot * (1.0f / D_MODEL) + 1e-5f);
  const float4 w = ((const float4*)nw)[threadIdx.x];
  ushort4 o;
  o.x = f2bf(v.x * rs * w.x);
  o.y = f2bf(v.y * rs * w.y);
  o.z = f2bf(v.z * rs * w.z);
  o.w = f2bf(v.w * rs * w.w);
  ((ushort4*)(xn + (size_t)row * D_MODEL))[threadIdx.x] = o;
}

__device__ __forceinline__ void tr_body(const float* __restrict__ W, unsigned short* __restrict__ Wt,
                                        int K, int N, int Npad, int bx, int by, float (*tile)[33]) {
  const int tx = threadIdx.x & 31, ty = threadIdx.x >> 5;
  const int kt = by * 32, nt = bx * 32;
  #pragma unroll
  for (int i = 0; i < 4; ++i) {
    const int k = kt + ty + i*8, n = nt + tx;
    tile[ty + i*8][tx] = (k < K && n < N) ? W[(size_t)k * N + n] : 0.0f;
  }
  __syncthreads();
  #pragma unroll
  for (int i = 0; i < 4; ++i) {
    const int n = nt + ty + i*8, k = kt + tx;
    if (n < Npad && k < K) Wt[(size_t)n * K + k] = f2bf(tile[tx][ty + i*8]);
  }
}

__global__ __launch_bounds__(256) void prep_fused_kernel(const float* x, const float* nw, unsigned short* xn,
                                                         const float* W1, unsigned short* W1t,
                                                         const float* W2, unsigned short* W2t,
                                                         const float* W3, unsigned short* W3t,
                                                         const float* W4, unsigned short* W4t) {
  __shared__ float shbuf[32][33];
  const int b = blockIdx.x;
  if (b < 4096) {
    rms_body(x, nw, xn, b, &shbuf[0][0]);
  } else if (b < 8192) {
    const int i = b - 4096;            // dim3(128,32): K=1024 N=4096
    tr_body(W1, W1t, 1024, 4096, 4096, i & 127, i >> 7, shbuf);
  } else if (b < 8448) {
    const int i = b - 8192;            // dim3(4,64): K=2048 N=96 pad 128
    tr_body(W2, W2t, 2048, 96, 128, i & 3, i >> 2, shbuf);
  } else if (b < 8576) {
    const int i = b - 8448;            // dim3(64,2): K=64 N=2048
    tr_body(W3, W3t, 64, 2048, 2048, i & 63, i >> 6, shbuf);
  } else {
    const int i = b - 8576;            // dim3(32,64): K=2048 N=1024
    tr_body(W4, W4t, 2048, 1024, 1024, i & 31, i >> 5, shbuf);
  }
}

// ---------------- GEMM body: C[M][N] = A[M][K] @ Bt[N][K]^T  (bf16 in, fp32 acc) ------
// 2-phase prefetch (T3-minimum): double-buffered LDS; issue next-tile global_load_lds
// BEFORE compute on current tile; single barrier per K-step (its implicit vmcnt-drain
// lands after MFMA instead of before).
// MODE 0: split -> xi_raw bf16 (col<2048), res bf16 (col>=2048). N=4096
// MODE 1: col<64 -> dr bf16 [M][64]; 64<=col<96 -> BC f32 [M][32]; else skip. N=128(pad)
// MODE 2: fast-softplus(v + dt_b[col]) -> delta bf16 [M][2048]. N=2048
// MODE 3: v + x[row][col] -> out f32 [M][1024]. N=1024
template<int MODE>
__device__ __forceinline__ void gemm_body(const unsigned short* __restrict__ A,
                                          const unsigned short* __restrict__ Bt,
                                          const int M, const int N, const int K,
                                          void* __restrict__ out0,
                                          void* __restrict__ out1,
                                          const float* __restrict__ extra) {
  __shared__ __align__(16) unsigned short sA[2][128 * 32];
  __shared__ __align__(16) unsigned short sB[2][128 * 32];
  const int tid = threadIdx.x;
  const int w = tid >> 6, lane = tid & 63;
  const int m0 = blockIdx.y * 128, n0 = blockIdx.x * 128;
  const int wm = w >> 1, wn = w & 1;
  const int lr = lane & 15, kq = lane >> 4;

  f32x4 acc[4][4] = {};

  // staging: LDS chunk p=(row,qlds) holds global (row, qlds ^ (row&3))  [4-way-conflict swizzle]
  const int r0 = tid >> 2;
  const int qb = ((tid & 3) ^ (r0 & 3)) * 16;      // source byte-in-row (swizzle-inverse)
  const char* pA0 = (const char*)A + ((size_t)(m0 + r0)      * K) * 2 + qb;
  const char* pA1 = (const char*)A + ((size_t)(m0 + r0 + 64) * K) * 2 + qb;
  const char* pB0 = (const char*)Bt + ((size_t)(n0 + r0)      * K) * 2 + qb;
  const char* pB1 = (const char*)Bt + ((size_t)(n0 + r0 + 64) * K) * 2 + qb;

  // fragment read offset (swizzled quarter)
  const int kqs = (kq ^ (lr & 3)) * 8;

  auto stage = [&](int p, int k0) {
    gload16(pA0 + (size_t)k0 * 2, (char*)sA[p] + w * 1024);
    gload16(pA1 + (size_t)k0 * 2, (char*)sA[p] + 4096 + w * 1024);
    gload16(pB0 + (size_t)k0 * 2, (char*)sB[p] + w * 1024);
    gload16(pB1 + (size_t)k0 * 2, (char*)sB[p] + 4096 + w * 1024);
  };
  auto compute = [&](int p) {
    const unsigned short* pa = sA[p] + (wm*64 + lr) * 32 + kqs;
    const unsigned short* pb = sB[p] + (wn*64 + lr) * 32 + kqs;
    bf16x8 af[4], bb[4];
    #pragma unroll
    for (int mf = 0; mf < 4; ++mf)
      af[mf] = __builtin_bit_cast(bf16x8, *(const s16x8*)(pa + mf * 16 * 32));
    #pragma unroll
    for (int nf = 0; nf < 4; ++nf)
      bb[nf] = __builtin_bit_cast(bf16x8, *(const s16x8*)(pb + nf * 16 * 32));
    #pragma unroll
    for (int mf = 0; mf < 4; ++mf)
      #pragma unroll
      for (int nf = 0; nf < 4; ++nf)
        acc[mf][nf] = __builtin_amdgcn_mfma_f32_16x16x32_bf16(af[mf], bb[nf], acc[mf][nf], 0, 0, 0);
  };

  stage(0, 0);
  __syncthreads();                 // implicit vmcnt(0) drain: buf0 ready
  int p = 0;
  for (int k0 = 32; k0 < K; k0 += 32) {
    stage(p ^ 1, k0);              // next tile in flight during compute
    compute(p);
    __syncthreads();               // drains vmcnt (buf p^1 ready) + readers done with buf p
    p ^= 1;
  }
  compute(p);

  #pragma unroll
  for (int mf = 0; mf < 4; ++mf) {
    #pragma unroll
    for (int nf = 0; nf < 4; ++nf) {
      #pragma unroll
      for (int r = 0; r < 4; ++r) {
        const int row = m0 + wm*64 + mf*16 + kq*4 + r;
        const int col = n0 + wn*64 + nf*16 + lr;
        const float v = acc[mf][nf][r];
        if constexpr (MODE == 0) {
          if (col < D_INNER) ((unsigned short*)out0)[(size_t)row * D_INNER + col] = f2bf(v);
          else               ((unsigned short*)out1)[(size_t)row * D_INNER + (col - D_INNER)] = f2bf(v);
        } else if constexpr (MODE == 1) {
          if (col < DT_RANK) ((unsigned short*)out0)[(size_t)row * DT_RANK + col] = f2bf(v);
          else if (col < DT_RANK + 2*NSTATE) ((float*)out1)[(size_t)row * (2*NSTATE) + (col - DT_RANK)] = v;
        } else if constexpr (MODE == 2) {
          const float t = v + extra[col];
          const float sp = (t > 30.0f) ? t : __logf(1.0f + __expf(t));
          ((unsigned short*)out0)[(size_t)row * D_INNER + col] = f2bf(sp);
        } else {
          ((float*)out0)[(size_t)row * D_MODEL + col] = v + extra[(size_t)row * D_MODEL + col];
        }
      }
    }
  }
}

// distinct names so rocprof top-5 discriminates the four GEMMs
__global__ __launch_bounds__(256) void g0_inproj_kernel(const unsigned short* A, const unsigned short* Bt,
                                                        int M, int N, int K, void* o0, void* o1, const float* ex) {
  gemm_body<0>(A, Bt, M, N, K, o0, o1, ex);
}
__global__ __launch_bounds__(256) void g1_xproj_kernel(const unsigned short* A, const unsigned short* Bt,
                                                       int M, int N, int K, void* o0, void* o1, const float* ex) {
  gemm_body<1>(A, Bt, M, N, K, o0, o1, ex);
}
__global__ __launch_bounds__(256) void g2_dtproj_kernel(const unsigned short* A, const unsigned short* Bt,
                                                        int M, int N, int K, void* o0, void* o1, const float* ex) {
  gemm_body<2>(A, Bt, M, N, K, o0, o1, ex);
}
__global__ __launch_bounds__(256) void g3_outproj_kernel(const unsigned short* A, const unsigned short* Bt,
                                                         int M, int N, int K, void* o0, void* o1, const float* ex) {
  gemm_body<3>(A, Bt, M, N, K, o0, o1, ex);
}

// ---------------- causal depthwise conv (width 4) + bias + SiLU, 8 ch/thread ------
__global__ __launch_bounds__(256) void conv_silu_kernel(const unsigned short* __restrict__ xi_raw,
                                                        const float* __restrict__ cw,
                                                        const float* __restrict__ cb,
                                                        unsigned short* __restrict__ xi) {
  const int t = blockIdx.x * 256 + threadIdx.x;   // NTOK*256 threads, 8 channels each
  const int d8 = (t & 255) * 8;
  const int row = t >> 8;                         // b*SEQ + l
  const int l = row & (SEQ - 1);

  float acc[8];
  #pragma unroll
  for (int c = 0; c < 8; c += 4) {
    const f32x4 bv = *(const f32x4*)(cb + d8 + c);
    acc[c+0] = bv[0]; acc[c+1] = bv[1]; acc[c+2] = bv[2]; acc[c+3] = bv[3];
  }
  f32x4 wv[8];
  #pragma unroll
  for (int c = 0; c < 8; ++c) wv[c] = ((const f32x4*)cw)[d8 + c];

  #pragma unroll
  for (int tap = 0; tap < 4; ++tap) {
    const int lp = l - 3 + tap;
    if (lp >= 0) {
      const s16x8 v = *(const s16x8*)(xi_raw + (size_t)(row - 3 + tap) * D_INNER + d8);
      #pragma unroll
      for (int c = 0; c < 8; ++c)
        acc[c] += wv[c][tap] * bf2f((unsigned short)v[c]);
    }
  }
  s16x8 o;
  #pragma unroll
  for (int c = 0; c < 8; ++c) {
    const float a = acc[c] / (1.0f + __expf(-acc[c]));
    o[c] = (short)f2bf(a);
  }
  *(s16x8*)(xi + (size_t)row * D_INNER + d8) = o;
}

// ---------------- chunked selective scan ----------------
template<int PASS>
__global__ __launch_bounds__(256) void scan_pass_kernel(const unsigned short* __restrict__ delta,
                                                        const unsigned short* __restrict__ xi,
                                                        const unsigned short* __restrict__ res,
                                                        const float* __restrict__ BC,
                                                        const float* __restrict__ A_log,
                                                        const float* __restrict__ Dv,
                                                        const float* __restrict__ initS,
                                                        float* __restrict__ aprodOut,
                                                        float* __restrict__ sendOut,
                                                        unsigned short* __restrict__ yg) {
  const int tid = threadIdx.x;
  const int db = blockIdx.x & 7;
  const int c  = (blockIdx.x >> 3) & (NC - 1);
  const int b  = blockIdx.x >> 8;
  const int d  = db * 256 + tid;
  const int row0 = b * SEQ + c * CHK;
  const size_t ob = ((size_t)(b * NC + c) * D_INNER + d) * 16;

  float Ac[16];
  #pragma unroll
  for (int q = 0; q < 4; ++q) {
    f32x4 t = ((const f32x4*)(A_log + (size_t)d * 16))[q];
    Ac[q*4+0] = -expf(t[0]); Ac[q*4+1] = -expf(t[1]);
    Ac[q*4+2] = -expf(t[2]); Ac[q*4+3] = -expf(t[3]);
  }
  float s[16];
  float ap[16];
  if constexpr (PASS == 0) {
    #pragma unroll
    for (int n = 0; n < 16; ++n) { s[n] = 0.0f; ap[n] = 1.0f; }
  } else {
    #pragma unroll
    for (int q = 0; q < 4; ++q)
      ((f32x4*)s)[q] = ((const f32x4*)(initS + ob))[q];
  }
  float Dd = 0.0f;
  if constexpr (PASS == 1) Dd = Dv[d];

  __shared__ float bcbuf[2][8][32];
  auto stageg = [&](int g, int p) {
    bcbuf[p][tid >> 5][tid & 31] = BC[(size_t)(row0 + g * 8) * 32 + tid];
  };
  stageg(0, 0);

  for (int g = 0; g < NGRP; ++g) {
    unsigned short dl[8], uu[8], rr[8];
    #pragma unroll
    for (int j = 0; j < 8; ++j) {
      const size_t row = (size_t)(row0 + g * 8 + j) * D_INNER + d;
      dl[j] = delta[row];
      uu[j] = xi[row];
      if constexpr (PASS == 1) rr[j] = res[row];
    }
    __syncthreads();
    if (g + 1 < NGRP) stageg(g + 1, (g + 1) & 1);

    #pragma unroll
    for (int j = 0; j < 8; ++j) {
      const float dlt = bf2f(dl[j]);
      const float u   = bf2f(uu[j]);
      const float dlu = dlt * u;
      float bc[32];
      #pragma unroll
      for (int q = 0; q < (PASS ? 8 : 4); ++q)
        ((f32x4*)bc)[q] = ((const f32x4*)(&bcbuf[g & 1][j][0]))[q];
      #pragma unroll
      for (int n = 0; n < 16; ++n) {
        const float dA = __expf(dlt * Ac[n]);
        s[n] = dA * s[n] + dlu * bc[n];
        if constexpr (PASS == 0) ap[n] *= dA;
      }
      if constexpr (PASS == 1) {
        float y = 0.0f;
        #pragma unroll
        for (int n = 0; n < 16; ++n) y += s[n] * bc[16 + n];
        const float r = bf2f(rr[j]);
        const float o = (y + u * Dd) * (r / (1.0f + __expf(-r)));
        yg[(size_t)(row0 + g * 8 + j) * D_INNER + d] = f2bf(o);
      }
    }
  }

  if constexpr (PASS == 0) {
    #pragma unroll
    for (int q = 0; q < 4; ++q) {
      ((f32x4*)(aprodOut + ob))[q] = ((f32x4*)ap)[q];
      ((f32x4*)(sendOut + ob))[q]  = ((f32x4*)s)[q];
    }
  }
}

// ---------------- combine chunk summaries: carry_c = state entering chunk c ----------
__global__ __launch_bounds__(256) void scan_combine_kernel(const float* __restrict__ aprod,
                                                           const float* __restrict__ send,
                                                           float* __restrict__ initS) {
  const int t = blockIdx.x * 256 + threadIdx.x;
  const int b = t >> 13;
  const int rq = t & 8191;
  f32x4 carry = {0.0f, 0.0f, 0.0f, 0.0f};
  #pragma unroll
  for (int c = 0; c < NC; ++c) {
    const size_t idx = (size_t)(b * NC + c) * 8192 + rq;
    ((f32x4*)initS)[idx] = carry;
    const f32x4 a = ((const f32x4*)aprod)[idx];
    const f32x4 e = ((const f32x4*)send)[idx];
    carry = a * carry + e;
  }
}

// ---------------- launcher ----------------
extern "C" void kernel_launch(void* const* d_in, const int* in_sizes, int n_in,
                              void* d_out, int out_size, void* d_ws, size_t ws_size,
                              hipStream_t stream) {
  const float* x        = (const float*)d_in[0];
  const float* in_proj  = (const float*)d_in[1];
  const float* conv_w   = (const float*)d_in[2];
  const float* conv_b   = (const float*)d_in[3];
  const float* x_proj   = (const float*)d_in[4];
  const float* dt_proj  = (const float*)d_in[5];
  const float* dt_b     = (const float*)d_in[6];
  const float* A_log    = (const float*)d_in[7];
  const float* Dv       = (const float*)d_in[8];
  const float* out_proj = (const float*)d_in[9];
  const float* norm_w   = (const float*)d_in[10];

  char* ws = (char*)d_ws;
  size_t off = 0;
  auto alloc = [&](size_t bytes) {
    char* p = ws + off; off += (bytes + 255) & ~(size_t)255; return p;
  };
  unsigned short* xn     = (unsigned short*)alloc((size_t)NTOK * D_MODEL * 2);   // 8 MB (reused as initS)
  unsigned short* W1t    = (unsigned short*)alloc((size_t)(2 * D_INNER) * D_MODEL * 2);
  unsigned short* xi_raw = (unsigned short*)alloc((size_t)NTOK * D_INNER * 2);   // 16 MB (reused: aprod+send)
  unsigned short* resb   = (unsigned short*)alloc((size_t)NTOK * D_INNER * 2);
  unsigned short* xi     = (unsigned short*)alloc((size_t)NTOK * D_INNER * 2);
  unsigned short* W2t    = (unsigned short*)alloc((size_t)128 * D_INNER * 2);
  unsigned short* dr     = (unsigned short*)alloc((size_t)NTOK * DT_RANK * 2);
  float*          BC     = (float*)alloc((size_t)NTOK * 32 * 4);
  unsigned short* W3t    = (unsigned short*)alloc((size_t)D_INNER * DT_RANK * 2);
  unsigned short* dlt    = (unsigned short*)alloc((size_t)NTOK * D_INNER * 2);
  unsigned short* ygb    = (unsigned short*)alloc((size_t)NTOK * D_INNER * 2);
  unsigned short* W4t    = (unsigned short*)alloc((size_t)D_MODEL * D_INNER * 2);

  // scratch reuse (dead-buffer overlays):
  //   aprod/send (8 MB each) overlay xi_raw (dead after conv)
  //   initS (8 MB) overlays xn (dead after GEMM1)
  float* aprod = (float*)xi_raw;
  float* send  = (float*)((char*)xi_raw + 8388608);
  float* initS = (float*)xn;

  prep_fused_kernel<<<10624, 256, 0, stream>>>(x, norm_w, xn,
                                               in_proj, W1t, x_proj, W2t,
                                               dt_proj, W3t, out_proj, W4t);

  g0_inproj_kernel<<<dim3(4096/128, 4096/128), 256, 0, stream>>>(xn, W1t, NTOK, 4096, 1024, xi_raw, resb, nullptr);
  conv_silu_kernel<<<NTOK, 256, 0, stream>>>(xi_raw, conv_w, conv_b, xi);
  g1_xproj_kernel<<<dim3(1, 4096/128), 256, 0, stream>>>(xi, W2t, NTOK, 128, 2048, dr, BC, nullptr);
  g2_dtproj_kernel<<<dim3(2048/128, 4096/128), 256, 0, stream>>>(dr, W3t, NTOK, 2048, 64, dlt, nullptr, dt_b);

  scan_pass_kernel<0><<<NBATCH * NC * (D_INNER/256), 256, 0, stream>>>(
      dlt, xi, nullptr, BC, A_log, nullptr, nullptr, aprod, send, nullptr);
  scan_combine_kernel<<<64, 256, 0, stream>>>(aprod, send, initS);
  scan_pass_kernel<1><<<NBATCH * NC * (D_INNER/256), 256, 0, stream>>>(
      dlt, xi, resb, BC, A_log, Dv, initS, nullptr, nullptr, ygb);

  g3_outproj_kernel<<<dim3(1024/128, 4096/128), 256, 0, stream>>>(ygb, W4t, NTOK, 1024, 2048, d_out, nullptr, x);
}

// Round 10
// 350.312 us; speedup vs baseline: 1.4615x; 1.0536x over previous
//
#include <hip/hip_runtime.h>
#include <cstdint>

#define D_MODEL 1024
#define D_INNER 2048
#define NSTATE  16
#define DT_RANK 64
#define SEQ     2048
#define NBATCH  2
#define NTOK    (NBATCH * SEQ)   // 4096

// chunked scan
#define NC      32               // chunks per sequence
#define CHK     64               // steps per chunk (NC*CHK == SEQ)
#define NGRP    8                // groups of 8 steps per chunk

typedef float  f32x4  __attribute__((ext_vector_type(4)));
typedef __bf16 bf16x8 __attribute__((ext_vector_type(8)));
typedef short  s16x8  __attribute__((ext_vector_type(8)));

__device__ __forceinline__ unsigned short f2bf(float f) {
  union { float f; uint32_t u; } a; a.f = f;
  uint32_t u = a.u;
  uint32_t r = (u + 0x7FFFu + ((u >> 16) & 1u)) >> 16;
  return (unsigned short)r;
}
__device__ __forceinline__ float bf2f(unsigned short h) {
  union { uint32_t u; float f; } a; a.u = ((uint32_t)h) << 16;
  return a.f;
}

__device__ __forceinline__ void gload16(const void* g, void* l) {
  __builtin_amdgcn_global_load_lds((__attribute__((address_space(1))) void*)g,
                                   (__attribute__((address_space(3))) void*)l,
                                   16, 0, 0);
}

// ---------------- fused prep: rmsnorm + 4 weight transposes, one launch ----------
__device__ __forceinline__ void rms_body(const float* __restrict__ x, const float* __restrict__ nw,
                                         unsigned short* __restrict__ xn, int row, float* red) {
  const float4 v = ((const float4*)(x + (size_t)row * D_MODEL))[threadIdx.x];
  float ss = v.x*v.x + v.y*v.y + v.z*v.z + v.w*v.w;
  #pragma unroll
  for (int m = 32; m; m >>= 1) ss += __shfl_xor(ss, m);
  if ((threadIdx.x & 63) == 0) red[threadIdx.x >> 6] = ss;
  __syncthreads();
  const float tot = red[0] + red[1] + red[2] + red[3];
  const float rs = rsqrtf(tot * (1.0f / D_MODEL) + 1e-5f);
  const float4 w = ((const float4*)nw)[threadIdx.x];
  ushort4 o;
  o.x = f2bf(v.x * rs * w.x);
  o.y = f2bf(v.y * rs * w.y);
  o.z = f2bf(v.z * rs * w.z);
  o.w = f2bf(v.w * rs * w.w);
  ((ushort4*)(xn + (size_t)row * D_MODEL))[threadIdx.x] = o;
}

__device__ __forceinline__ void tr_body(const float* __restrict__ W, unsigned short* __restrict__ Wt,
                                        int K, int N, int Npad, int bx, int by, float (*tile)[33]) {
  const int tx = threadIdx.x & 31, ty = threadIdx.x >> 5;
  const int kt = by * 32, nt = bx * 32;
  #pragma unroll
  for (int i = 0; i < 4; ++i) {
    const int k = kt + ty + i*8, n = nt + tx;
    tile[ty + i*8][tx] = (k < K && n < N) ? W[(size_t)k * N + n] : 0.0f;
  }
  __syncthreads();
  #pragma unroll
  for (int i = 0; i < 4; ++i) {
    const int n = nt + ty + i*8, k = kt + tx;
    if (n < Npad && k < K) Wt[(size_t)n * K + k] = f2bf(tile[tx][ty + i*8]);
  }
}

__global__ __launch_bounds__(256) void prep_fused_kernel(const float* x, const float* nw, unsigned short* xn,
                                                         const float* W1, unsigned short* W1t,
                                                         const float* W2, unsigned short* W2t,
                                                         const float* W3, unsigned short* W3t,
                                                         const float* W4, unsigned short* W4t) {
  __shared__ float shbuf[32][33];
  const int b = blockIdx.x;
  if (b < 4096) {
    rms_body(x, nw, xn, b, &shbuf[0][0]);
  } else if (b < 8192) {
    const int i = b - 4096;            // dim3(128,32): K=1024 N=4096
    tr_body(W1, W1t, 1024, 4096, 4096, i & 127, i >> 7, shbuf);
  } else if (b < 8448) {
    const int i = b - 8192;            // dim3(4,64): K=2048 N=96 pad 128
    tr_body(W2, W2t, 2048, 96, 128, i & 3, i >> 2, shbuf);
  } else if (b < 8576) {
    const int i = b - 8448;            // dim3(64,2): K=64 N=2048
    tr_body(W3, W3t, 64, 2048, 2048, i & 63, i >> 6, shbuf);
  } else {
    const int i = b - 8576;            // dim3(32,64): K=2048 N=1024
    tr_body(W4, W4t, 2048, 1024, 1024, i & 31, i >> 5, shbuf);
  }
}

// ================= g0: 256x256 / BK=64 / 8-wave / 4-phase pipelined GEMM =========
// C[M][N] = A[M][K] @ Bt[N][K]^T, M=N=4096, K=1024. Split output at col 2048.
// LDS: double-buffered A/B K-tiles (128 KB). T2 XOR swizzle: logical 16B slot c of
// row r lives at phys slot c ^ ((r&7)<<4); global_load_lds dest stays LINEAR, the
// global SOURCE is inverse-swizzled (rule #21), ds_read applies the same XOR.
// Per K-tile: 4 phases {ds_read subtile | stage 2 gload_lds -> s_barrier ->
// setprio(1) 16 MFMA setprio(0) -> s_barrier}; one __syncthreads (vmcnt publish)
// per K-tile, so loads issued in phases 0..3 get a full tile of MFMA cover.
__global__ __launch_bounds__(512, 2) void g0_inproj_kernel(const unsigned short* __restrict__ A,
                                                           const unsigned short* __restrict__ Bt,
                                                           unsigned short* __restrict__ xiOut,
                                                           unsigned short* __restrict__ resOut) {
  constexpr int K  = 1024;
  constexpr int NT = K / 64;                 // 16 K-tiles
  __shared__ __align__(16) unsigned short sA[2][256 * 64];   // 32 KB per buffer
  __shared__ __align__(16) unsigned short sB[2][256 * 64];
  const int tid = threadIdx.x;
  const int wid = tid >> 6, lane = tid & 63;
  const int wm = wid >> 2, wn = wid & 3;     // 2 x 4 waves; wave tile 128 x 64
  const int lr = lane & 15, kq = lane >> 4;
  const int m0 = blockIdx.y * 256, n0 = blockIdx.x * 256;

  f32x4 acc[8][4] = {};

  // ---- staging: thread t fills phys LDS bytes [i*8192 + t*16), i=0..3 per matrix.
  // phys row = i*64 + (t>>3); phys slot = (t&7)*16; source col elems = 8*((t&7)^((t>>3)&7))
  const int srow = tid >> 3;
  const int scol = 8 * ((tid & 7) ^ ((tid >> 3) & 7));
  const unsigned short* gA = A  + (size_t)(m0 + srow) * K + scol;
  const unsigned short* gB = Bt + (size_t)(n0 + srow) * K + scol;

  // ---- ds_read offsets (elems). logical col bytes c = ks*64 + kq*16, phys = c ^ ((lr&7)<<4)
  const int xsw = (lr & 7) << 4;
  const int cofs0 = ((kq * 16) ^ xsw) >> 1;          // ks = 0
  const int cofs1 = ((64 + kq * 16) ^ xsw) >> 1;     // ks = 1
  const int aRow = (wm * 128 + lr) * 64;
  const int bRow = (wn * 64 + lr) * 64;

  auto stage2 = [&](int p, int kt, int q) {
    const int k0 = kt * 64;
    gload16(gA + (size_t)q * 64 * K + k0, (char*)sA[p] + q * 8192 + tid * 16);
    gload16(gB + (size_t)q * 64 * K + k0, (char*)sB[p] + q * 8192 + tid * 16);
  };

  // prologue: fully stage K-tile 0 into buffer 0
  #pragma unroll
  for (int q = 0; q < 4; ++q) stage2(0, 0, q);
  __syncthreads();

  int p = 0;
  for (int kt = 0; kt < NT; ++kt) {
    const unsigned short* SA = sA[p];
    const unsigned short* SB = sB[p];
    bf16x8 b[4][2];
    #pragma unroll
    for (int q = 0; q < 4; ++q) {
      // ds-load this phase's A sub-frags (and all B frags in phase 0)
      bf16x8 a[2][2];
      #pragma unroll
      for (int mi = 0; mi < 2; ++mi) {
        a[mi][0] = __builtin_bit_cast(bf16x8, *(const s16x8*)(SA + aRow + (2*q + mi) * 1024 + cofs0));
        a[mi][1] = __builtin_bit_cast(bf16x8, *(const s16x8*)(SA + aRow + (2*q + mi) * 1024 + cofs1));
      }
      if (q == 0) {
        #pragma unroll
        for (int nf = 0; nf < 4; ++nf) {
          b[nf][0] = __builtin_bit_cast(bf16x8, *(const s16x8*)(SB + bRow + nf * 1024 + cofs0));
          b[nf][1] = __builtin_bit_cast(bf16x8, *(const s16x8*)(SB + bRow + nf * 1024 + cofs1));
        }
      }
      // stage one chunk of next K-tile into the other buffer
      if (kt + 1 < NT) stage2(p ^ 1, kt + 1, q);
      __builtin_amdgcn_s_barrier();
      __builtin_amdgcn_s_setprio(1);
      #pragma unroll
      for (int ks = 0; ks < 2; ++ks)
        #pragma unroll
        for (int mi = 0; mi < 2; ++mi)
          #pragma unroll
          for (int nf = 0; nf < 4; ++nf)
            acc[2*q + mi][nf] = __builtin_amdgcn_mfma_f32_16x16x32_bf16(a[mi][ks], b[nf][ks], acc[2*q + mi][nf], 0, 0, 0);
      __builtin_amdgcn_s_setprio(0);
      __builtin_amdgcn_s_barrier();
    }
    __syncthreads();               // drains vmcnt: buffer p^1 published for next tile
    p ^= 1;
  }

  // epilogue: split store at col 2048 (frag-uniform: 16-col frags never straddle)
  #pragma unroll
  for (int mf = 0; mf < 8; ++mf) {
    #pragma unroll
    for (int nf = 0; nf < 4; ++nf) {
      const int col = n0 + wn * 64 + nf * 16 + lr;
      unsigned short* dst = (col < D_INNER)
          ? xiOut + col
          : resOut + (col - D_INNER);
      #pragma unroll
      for (int r = 0; r < 4; ++r) {
        const int row = m0 + wm * 128 + mf * 16 + kq * 4 + r;
        dst[(size_t)row * D_INNER] = f2bf(acc[mf][nf][r]);
      }
    }
  }
}

// ---------------- GEMM body (128^2, 2-phase): used by g1/g2/g3 ----------------
// MODE 1: col<64 -> dr bf16 [M][64]; 64<=col<96 -> BC f32 [M][32]; else skip. N=128(pad)
// MODE 2: fast-softplus(v + dt_b[col]) -> delta bf16 [M][2048]. N=2048
// MODE 3: v + x[row][col] -> out f32 [M][1024]. N=1024
template<int MODE>
__device__ __forceinline__ void gemm_body(const unsigned short* __restrict__ A,
                                          const unsigned short* __restrict__ Bt,
                                          const int M, const int N, const int K,
                                          void* __restrict__ out0,
                                          void* __restrict__ out1,
                                          const float* __restrict__ extra) {
  __shared__ __align__(16) unsigned short sA[2][128 * 32];
  __shared__ __align__(16) unsigned short sB[2][128 * 32];
  const int tid = threadIdx.x;
  const int w = tid >> 6, lane = tid & 63;
  const int m0 = blockIdx.y * 128, n0 = blockIdx.x * 128;
  const int wm = w >> 1, wn = w & 1;
  const int lr = lane & 15, kq = lane >> 4;

  f32x4 acc[4][4] = {};

  const int r0 = tid >> 2;
  const int qb = ((tid & 3) ^ (r0 & 3)) * 16;
  const char* pA0 = (const char*)A + ((size_t)(m0 + r0)      * K) * 2 + qb;
  const char* pA1 = (const char*)A + ((size_t)(m0 + r0 + 64) * K) * 2 + qb;
  const char* pB0 = (const char*)Bt + ((size_t)(n0 + r0)      * K) * 2 + qb;
  const char* pB1 = (const char*)Bt + ((size_t)(n0 + r0 + 64) * K) * 2 + qb;

  const int kqs = (kq ^ (lr & 3)) * 8;

  auto stage = [&](int p, int k0) {
    gload16(pA0 + (size_t)k0 * 2, (char*)sA[p] + w * 1024);
    gload16(pA1 + (size_t)k0 * 2, (char*)sA[p] + 4096 + w * 1024);
    gload16(pB0 + (size_t)k0 * 2, (char*)sB[p] + w * 1024);
    gload16(pB1 + (size_t)k0 * 2, (char*)sB[p] + 4096 + w * 1024);
  };
  auto compute = [&](int p) {
    const unsigned short* pa = sA[p] + (wm*64 + lr) * 32 + kqs;
    const unsigned short* pb = sB[p] + (wn*64 + lr) * 32 + kqs;
    bf16x8 af[4], bb[4];
    #pragma unroll
    for (int mf = 0; mf < 4; ++mf)
      af[mf] = __builtin_bit_cast(bf16x8, *(const s16x8*)(pa + mf * 16 * 32));
    #pragma unroll
    for (int nf = 0; nf < 4; ++nf)
      bb[nf] = __builtin_bit_cast(bf16x8, *(const s16x8*)(pb + nf * 16 * 32));
    #pragma unroll
    for (int mf = 0; mf < 4; ++mf)
      #pragma unroll
      for (int nf = 0; nf < 4; ++nf)
        acc[mf][nf] = __builtin_amdgcn_mfma_f32_16x16x32_bf16(af[mf], bb[nf], acc[mf][nf], 0, 0, 0);
  };

  stage(0, 0);
  __syncthreads();
  int p = 0;
  for (int k0 = 32; k0 < K; k0 += 32) {
    stage(p ^ 1, k0);
    compute(p);
    __syncthreads();
    p ^= 1;
  }
  compute(p);

  #pragma unroll
  for (int mf = 0; mf < 4; ++mf) {
    #pragma unroll
    for (int nf = 0; nf < 4; ++nf) {
      #pragma unroll
      for (int r = 0; r < 4; ++r) {
        const int row = m0 + wm*64 + mf*16 + kq*4 + r;
        const int col = n0 + wn*64 + nf*16 + lr;
        const float v = acc[mf][nf][r];
        if constexpr (MODE == 1) {
          if (col < DT_RANK) ((unsigned short*)out0)[(size_t)row * DT_RANK + col] = f2bf(v);
          else if (col < DT_RANK + 2*NSTATE) ((float*)out1)[(size_t)row * (2*NSTATE) + (col - DT_RANK)] = v;
        } else if constexpr (MODE == 2) {
          const float t = v + extra[col];
          const float sp = (t > 30.0f) ? t : __logf(1.0f + __expf(t));
          ((unsigned short*)out0)[(size_t)row * D_INNER + col] = f2bf(sp);
        } else {
          ((float*)out0)[(size_t)row * D_MODEL + col] = v + extra[(size_t)row * D_MODEL + col];
        }
      }
    }
  }
}

__global__ __launch_bounds__(256) void g1_xproj_kernel(const unsigned short* A, const unsigned short* Bt,
                                                       int M, int N, int K, void* o0, void* o1, const float* ex) {
  gemm_body<1>(A, Bt, M, N, K, o0, o1, ex);
}
__global__ __launch_bounds__(256) void g2_dtproj_kernel(const unsigned short* A, const unsigned short* Bt,
                                                        int M, int N, int K, void* o0, void* o1, const float* ex) {
  gemm_body<2>(A, Bt, M, N, K, o0, o1, ex);
}
__global__ __launch_bounds__(256) void g3_outproj_kernel(const unsigned short* A, const unsigned short* Bt,
                                                         int M, int N, int K, void* o0, void* o1, const float* ex) {
  gemm_body<3>(A, Bt, M, N, K, o0, o1, ex);
}

// ---------------- causal depthwise conv (width 4) + bias + SiLU, 8 ch/thread ------
__global__ __launch_bounds__(256) void conv_silu_kernel(const unsigned short* __restrict__ xi_raw,
                                                        const float* __restrict__ cw,
                                                        const float* __restrict__ cb,
                                                        unsigned short* __restrict__ xi) {
  const int t = blockIdx.x * 256 + threadIdx.x;
  const int d8 = (t & 255) * 8;
  const int row = t >> 8;
  const int l = row & (SEQ - 1);

  float acc[8];
  #pragma unroll
  for (int c = 0; c < 8; c += 4) {
    const f32x4 bv = *(const f32x4*)(cb + d8 + c);
    acc[c+0] = bv[0]; acc[c+1] = bv[1]; acc[c+2] = bv[2]; acc[c+3] = bv[3];
  }
  f32x4 wv[8];
  #pragma unroll
  for (int c = 0; c < 8; ++c) wv[c] = ((const f32x4*)cw)[d8 + c];

  #pragma unroll
  for (int tap = 0; tap < 4; ++tap) {
    const int lp = l - 3 + tap;
    if (lp >= 0) {
      const s16x8 v = *(const s16x8*)(xi_raw + (size_t)(row - 3 + tap) * D_INNER + d8);
      #pragma unroll
      for (int c = 0; c < 8; ++c)
        acc[c] += wv[c][tap] * bf2f((unsigned short)v[c]);
    }
  }
  s16x8 o;
  #pragma unroll
  for (int c = 0; c < 8; ++c) {
    const float a = acc[c] / (1.0f + __expf(-acc[c]));
    o[c] = (short)f2bf(a);
  }
  *(s16x8*)(xi + (size_t)row * D_INNER + d8) = o;
}

// ---------------- chunked selective scan ----------------
template<int PASS>
__global__ __launch_bounds__(256) void scan_pass_kernel(const unsigned short* __restrict__ delta,
                                                        const unsigned short* __restrict__ xi,
                                                        const unsigned short* __restrict__ res,
                                                        const float* __restrict__ BC,
                                                        const float* __restrict__ A_log,
                                                        const float* __restrict__ Dv,
                                                        const float* __restrict__ initS,
                                                        float* __restrict__ aprodOut,
                                                        float* __restrict__ sendOut,
                                                        unsigned short* __restrict__ yg) {
  const int tid = threadIdx.x;
  const int db = blockIdx.x & 7;
  const int c  = (blockIdx.x >> 3) & (NC - 1);
  const int b  = blockIdx.x >> 8;
  const int d  = db * 256 + tid;
  const int row0 = b * SEQ + c * CHK;
  const size_t ob = ((size_t)(b * NC + c) * D_INNER + d) * 16;

  float Ac[16];
  #pragma unroll
  for (int q = 0; q < 4; ++q) {
    f32x4 t = ((const f32x4*)(A_log + (size_t)d * 16))[q];
    Ac[q*4+0] = -expf(t[0]); Ac[q*4+1] = -expf(t[1]);
    Ac[q*4+2] = -expf(t[2]); Ac[q*4+3] = -expf(t[3]);
  }
  float s[16];
  float ap[16];
  if constexpr (PASS == 0) {
    #pragma unroll
    for (int n = 0; n < 16; ++n) { s[n] = 0.0f; ap[n] = 1.0f; }
  } else {
    #pragma unroll
    for (int q = 0; q < 4; ++q)
      ((f32x4*)s)[q] = ((const f32x4*)(initS + ob))[q];
  }
  float Dd = 0.0f;
  if constexpr (PASS == 1) Dd = Dv[d];

  __shared__ float bcbuf[2][8][32];
  auto stageg = [&](int g, int p) {
    bcbuf[p][tid >> 5][tid & 31] = BC[(size_t)(row0 + g * 8) * 32 + tid];
  };
  stageg(0, 0);

  for (int g = 0; g < NGRP; ++g) {
    unsigned short dl[8], uu[8], rr[8];
    #pragma unroll
    for (int j = 0; j < 8; ++j) {
      const size_t row = (size_t)(row0 + g * 8 + j) * D_INNER + d;
      dl[j] = delta[row];
      uu[j] = xi[row];
      if constexpr (PASS == 1) rr[j] = res[row];
    }
    __syncthreads();
    if (g + 1 < NGRP) stageg(g + 1, (g + 1) & 1);

    #pragma unroll
    for (int j = 0; j < 8; ++j) {
      const float dlt = bf2f(dl[j]);
      const float u   = bf2f(uu[j]);
      const float dlu = dlt * u;
      float bc[32];
      #pragma unroll
      for (int q = 0; q < (PASS ? 8 : 4); ++q)
        ((f32x4*)bc)[q] = ((const f32x4*)(&bcbuf[g & 1][j][0]))[q];
      #pragma unroll
      for (int n = 0; n < 16; ++n) {
        const float dA = __expf(dlt * Ac[n]);
        s[n] = dA * s[n] + dlu * bc[n];
        if constexpr (PASS == 0) ap[n] *= dA;
      }
      if constexpr (PASS == 1) {
        float y = 0.0f;
        #pragma unroll
        for (int n = 0; n < 16; ++n) y += s[n] * bc[16 + n];
        const float r = bf2f(rr[j]);
        const float o = (y + u * Dd) * (r / (1.0f + __expf(-r)));
        yg[(size_t)(row0 + g * 8 + j) * D_INNER + d] = f2bf(o);
      }
    }
  }

  if constexpr (PASS == 0) {
    #pragma unroll
    for (int q = 0; q < 4; ++q) {
      ((f32x4*)(aprodOut + ob))[q] = ((f32x4*)ap)[q];
      ((f32x4*)(sendOut + ob))[q]  = ((f32x4*)s)[q];
    }
  }
}

// ---------------- combine chunk summaries ----------------
__global__ __launch_bounds__(256) void scan_combine_kernel(const float* __restrict__ aprod,
                                                           const float* __restrict__ send,
                                                           float* __restrict__ initS) {
  const int t = blockIdx.x * 256 + threadIdx.x;
  const int b = t >> 13;
  const int rq = t & 8191;
  f32x4 carry = {0.0f, 0.0f, 0.0f, 0.0f};
  #pragma unroll
  for (int c = 0; c < NC; ++c) {
    const size_t idx = (size_t)(b * NC + c) * 8192 + rq;
    ((f32x4*)initS)[idx] = carry;
    const f32x4 a = ((const f32x4*)aprod)[idx];
    const f32x4 e = ((const f32x4*)send)[idx];
    carry = a * carry + e;
  }
}

// ---------------- launcher ----------------
extern "C" void kernel_launch(void* const* d_in, const int* in_sizes, int n_in,
                              void* d_out, int out_size, void* d_ws, size_t ws_size,
                              hipStream_t stream) {
  const float* x        = (const float*)d_in[0];
  const float* in_proj  = (const float*)d_in[1];
  const float* conv_w   = (const float*)d_in[2];
  const float* conv_b   = (const float*)d_in[3];
  const float* x_proj   = (const float*)d_in[4];
  const float* dt_proj  = (const float*)d_in[5];
  const float* dt_b     = (const float*)d_in[6];
  const float* A_log    = (const float*)d_in[7];
  const float* Dv       = (const float*)d_in[8];
  const float* out_proj = (const float*)d_in[9];
  const float* norm_w   = (const float*)d_in[10];

  char* ws = (char*)d_ws;
  size_t off = 0;
  auto alloc = [&](size_t bytes) {
    char* p = ws + off; off += (bytes + 255) & ~(size_t)255; return p;
  };
  unsigned short* xn     = (unsigned short*)alloc((size_t)NTOK * D_MODEL * 2);   // 8 MB (reused as initS)
  unsigned short* W1t    = (unsigned short*)alloc((size_t)(2 * D_INNER) * D_MODEL * 2);
  unsigned short* xi_raw = (unsigned short*)alloc((size_t)NTOK * D_INNER * 2);   // 16 MB (reused: aprod+send)
  unsigned short* resb   = (unsigned short*)alloc((size_t)NTOK * D_INNER * 2);
  unsigned short* xi     = (unsigned short*)alloc((size_t)NTOK * D_INNER * 2);
  unsigned short* W2t    = (unsigned short*)alloc((size_t)128 * D_INNER * 2);
  unsigned short* dr     = (unsigned short*)alloc((size_t)NTOK * DT_RANK * 2);
  float*          BC     = (float*)alloc((size_t)NTOK * 32 * 4);
  unsigned short* W3t    = (unsigned short*)alloc((size_t)D_INNER * DT_RANK * 2);
  unsigned short* dlt    = (unsigned short*)alloc((size_t)NTOK * D_INNER * 2);
  unsigned short* ygb    = (unsigned short*)alloc((size_t)NTOK * D_INNER * 2);
  unsigned short* W4t    = (unsigned short*)alloc((size_t)D_MODEL * D_INNER * 2);

  float* aprod = (float*)xi_raw;
  float* send  = (float*)((char*)xi_raw + 8388608);
  float* initS = (float*)xn;

  prep_fused_kernel<<<10624, 256, 0, stream>>>(x, norm_w, xn,
                                               in_proj, W1t, x_proj, W2t,
                                               dt_proj, W3t, out_proj, W4t);

  g0_inproj_kernel<<<dim3(4096/256, 4096/256), 512, 0, stream>>>(xn, W1t, xi_raw, resb);
  conv_silu_kernel<<<NTOK, 256, 0, stream>>>(xi_raw, conv_w, conv_b, xi);
  g1_xproj_kernel<<<dim3(1, 4096/128), 256, 0, stream>>>(xi, W2t, NTOK, 128, 2048, dr, BC, nullptr);
  g2_dtproj_kernel<<<dim3(2048/128, 4096/128), 256, 0, stream>>>(dr, W3t, NTOK, 2048, 64, dlt, nullptr, dt_b);

  scan_pass_kernel<0><<<NBATCH * NC * (D_INNER/256), 256, 0, stream>>>(
      dlt, xi, nullptr, BC, A_log, nullptr, nullptr, aprod, send, nullptr);
  scan_combine_kernel<<<64, 256, 0, stream>>>(aprod, send, initS);
  scan_pass_kernel<1><<<NBATCH * NC * (D_INNER/256), 256, 0, stream>>>(
      dlt, xi, resb, BC, A_log, Dv, initS, nullptr, nullptr, ygb);

  g3_outproj_kernel<<<dim3(1024/128, 4096/128), 256, 0, stream>>>(ygb, W4t, NTOK, 1024, 2048, d_out, nullptr, x);
}

// Round 11
// 331.153 us; speedup vs baseline: 1.5460x; 1.0579x over previous
//
#include <hip/hip_runtime.h>
#include <cstdint>

#define D_MODEL 1024
#define D_INNER 2048
#define NSTATE  16
#define DT_RANK 64
#define SEQ     2048
#define NBATCH  2
#define NTOK    (NBATCH * SEQ)   // 4096

// chunked scan
#define NC      32               // chunks per sequence
#define CHK     64               // steps per chunk (NC*CHK == SEQ)
#define NGRP    8                // groups of 8 steps per chunk

typedef float  f32x4  __attribute__((ext_vector_type(4)));
typedef __bf16 bf16x8 __attribute__((ext_vector_type(8)));
typedef short  s16x8  __attribute__((ext_vector_type(8)));

__device__ __forceinline__ unsigned short f2bf(float f) {
  union { float f; uint32_t u; } a; a.f = f;
  uint32_t u = a.u;
  uint32_t r = (u + 0x7FFFu + ((u >> 16) & 1u)) >> 16;
  return (unsigned short)r;
}
__device__ __forceinline__ float bf2f(unsigned short h) {
  union { uint32_t u; float f; } a; a.u = ((uint32_t)h) << 16;
  return a.f;
}

__device__ __forceinline__ void gload16(const void* g, void* l) {
  __builtin_amdgcn_global_load_lds((__attribute__((address_space(1))) void*)g,
                                   (__attribute__((address_space(3))) void*)l,
                                   16, 0, 0);
}

// ---------------- fused prep: rmsnorm + 4 weight transposes, one launch ----------
__device__ __forceinline__ void rms_body(const float* __restrict__ x, const float* __restrict__ nw,
                                         unsigned short* __restrict__ xn, int row, float* red) {
  const float4 v = ((const float4*)(x + (size_t)row * D_MODEL))[threadIdx.x];
  float ss = v.x*v.x + v.y*v.y + v.z*v.z + v.w*v.w;
  #pragma unroll
  for (int m = 32; m; m >>= 1) ss += __shfl_xor(ss, m);
  if ((threadIdx.x & 63) == 0) red[threadIdx.x >> 6] = ss;
  __syncthreads();
  const float tot = red[0] + red[1] + red[2] + red[3];
  const float rs = rsqrtf(tot * (1.0f / D_MODEL) + 1e-5f);
  const float4 w = ((const float4*)nw)[threadIdx.x];
  ushort4 o;
  o.x = f2bf(v.x * rs * w.x);
  o.y = f2bf(v.y * rs * w.y);
  o.z = f2bf(v.z * rs * w.z);
  o.w = f2bf(v.w * rs * w.w);
  ((ushort4*)(xn + (size_t)row * D_MODEL))[threadIdx.x] = o;
}

__device__ __forceinline__ void tr_body(const float* __restrict__ W, unsigned short* __restrict__ Wt,
                                        int K, int N, int Npad, int bx, int by, float (*tile)[33]) {
  const int tx = threadIdx.x & 31, ty = threadIdx.x >> 5;
  const int kt = by * 32, nt = bx * 32;
  #pragma unroll
  for (int i = 0; i < 4; ++i) {
    const int k = kt + ty + i*8, n = nt + tx;
    tile[ty + i*8][tx] = (k < K && n < N) ? W[(size_t)k * N + n] : 0.0f;
  }
  __syncthreads();
  #pragma unroll
  for (int i = 0; i < 4; ++i) {
    const int n = nt + ty + i*8, k = kt + tx;
    if (n < Npad && k < K) Wt[(size_t)n * K + k] = f2bf(tile[tx][ty + i*8]);
  }
}

__global__ __launch_bounds__(256) void prep_fused_kernel(const float* x, const float* nw, unsigned short* xn,
                                                         const float* W1, unsigned short* W1t,
                                                         const float* W2, unsigned short* W2t,
                                                         const float* W3, unsigned short* W3t,
                                                         const float* W4, unsigned short* W4t) {
  __shared__ float shbuf[32][33];
  const int b = blockIdx.x;
  if (b < 4096) {
    rms_body(x, nw, xn, b, &shbuf[0][0]);
  } else if (b < 8192) {
    const int i = b - 4096;            // dim3(128,32): K=1024 N=4096
    tr_body(W1, W1t, 1024, 4096, 4096, i & 127, i >> 7, shbuf);
  } else if (b < 8448) {
    const int i = b - 8192;            // dim3(4,64): K=2048 N=96 pad 128
    tr_body(W2, W2t, 2048, 96, 128, i & 3, i >> 2, shbuf);
  } else if (b < 8576) {
    const int i = b - 8448;            // dim3(64,2): K=64 N=2048
    tr_body(W3, W3t, 64, 2048, 2048, i & 63, i >> 6, shbuf);
  } else {
    const int i = b - 8576;            // dim3(32,64): K=2048 N=1024
    tr_body(W4, W4t, 2048, 1024, 1024, i & 31, i >> 5, shbuf);
  }
}

// ================= g0: 256x256 / BK=64 / 8-wave / 4-phase pipelined GEMM =========
// (unchanged from round 8 — measured 63 -> ~44 us)
__global__ __launch_bounds__(512, 2) void g0_inproj_kernel(const unsigned short* __restrict__ A,
                                                           const unsigned short* __restrict__ Bt,
                                                           unsigned short* __restrict__ xiOut,
                                                           unsigned short* __restrict__ resOut) {
  constexpr int K  = 1024;
  constexpr int NT = K / 64;                 // 16 K-tiles
  __shared__ __align__(16) unsigned short sA[2][256 * 64];   // 32 KB per buffer
  __shared__ __align__(16) unsigned short sB[2][256 * 64];
  const int tid = threadIdx.x;
  const int wid = tid >> 6, lane = tid & 63;
  const int wm = wid >> 2, wn = wid & 3;     // 2 x 4 waves; wave tile 128 x 64
  const int lr = lane & 15, kq = lane >> 4;
  const int m0 = blockIdx.y * 256, n0 = blockIdx.x * 256;

  f32x4 acc[8][4] = {};

  const int srow = tid >> 3;
  const int scol = 8 * ((tid & 7) ^ ((tid >> 3) & 7));
  const unsigned short* gA = A  + (size_t)(m0 + srow) * K + scol;
  const unsigned short* gB = Bt + (size_t)(n0 + srow) * K + scol;

  const int xsw = (lr & 7) << 4;
  const int cofs0 = ((kq * 16) ^ xsw) >> 1;          // ks = 0
  const int cofs1 = ((64 + kq * 16) ^ xsw) >> 1;     // ks = 1
  const int aRow = (wm * 128 + lr) * 64;
  const int bRow = (wn * 64 + lr) * 64;

  auto stage2 = [&](int p, int kt, int q) {
    const int k0 = kt * 64;
    gload16(gA + (size_t)q * 64 * K + k0, (char*)sA[p] + q * 8192 + tid * 16);
    gload16(gB + (size_t)q * 64 * K + k0, (char*)sB[p] + q * 8192 + tid * 16);
  };

  #pragma unroll
  for (int q = 0; q < 4; ++q) stage2(0, 0, q);
  __syncthreads();

  int p = 0;
  for (int kt = 0; kt < NT; ++kt) {
    const unsigned short* SA = sA[p];
    const unsigned short* SB = sB[p];
    bf16x8 b[4][2];
    #pragma unroll
    for (int q = 0; q < 4; ++q) {
      bf16x8 a[2][2];
      #pragma unroll
      for (int mi = 0; mi < 2; ++mi) {
        a[mi][0] = __builtin_bit_cast(bf16x8, *(const s16x8*)(SA + aRow + (2*q + mi) * 1024 + cofs0));
        a[mi][1] = __builtin_bit_cast(bf16x8, *(const s16x8*)(SA + aRow + (2*q + mi) * 1024 + cofs1));
      }
      if (q == 0) {
        #pragma unroll
        for (int nf = 0; nf < 4; ++nf) {
          b[nf][0] = __builtin_bit_cast(bf16x8, *(const s16x8*)(SB + bRow + nf * 1024 + cofs0));
          b[nf][1] = __builtin_bit_cast(bf16x8, *(const s16x8*)(SB + bRow + nf * 1024 + cofs1));
        }
      }
      if (kt + 1 < NT) stage2(p ^ 1, kt + 1, q);
      __builtin_amdgcn_s_barrier();
      __builtin_amdgcn_s_setprio(1);
      #pragma unroll
      for (int ks = 0; ks < 2; ++ks)
        #pragma unroll
        for (int mi = 0; mi < 2; ++mi)
          #pragma unroll
          for (int nf = 0; nf < 4; ++nf)
            acc[2*q + mi][nf] = __builtin_amdgcn_mfma_f32_16x16x32_bf16(a[mi][ks], b[nf][ks], acc[2*q + mi][nf], 0, 0, 0);
      __builtin_amdgcn_s_setprio(0);
      __builtin_amdgcn_s_barrier();
    }
    __syncthreads();
    p ^= 1;
  }

  #pragma unroll
  for (int mf = 0; mf < 8; ++mf) {
    #pragma unroll
    for (int nf = 0; nf < 4; ++nf) {
      const int col = n0 + wn * 64 + nf * 16 + lr;
      unsigned short* dst = (col < D_INNER)
          ? xiOut + col
          : resOut + (col - D_INNER);
      #pragma unroll
      for (int r = 0; r < 4; ++r) {
        const int row = m0 + wm * 128 + mf * 16 + kq * 4 + r;
        dst[(size_t)row * D_INNER] = f2bf(acc[mf][nf][r]);
      }
    }
  }
}

// ---------------- GEMM body (128^2, BK=64, 2-phase dbuf): used by g1/g2/g3 -------
// Round-11 changes vs round-10: (a) BK 32->64 (half the K-steps / barrier drains);
// (b) full 8-slot XOR swizzle (row r, 16B slot s at phys s^(r&7); linear gload dest,
//     inverse-swizzled global source, XOR'd ds_read -> 2 lanes/slot = conflict-free);
// (c) bijective XCD-chunk block remap (nwg%8==0 for all three callers).
// MODE 1: col<64 -> dr bf16 [M][64]; 64<=col<96 -> BC f32 [M][32]; else skip. N=128(pad)
// MODE 2: fast-softplus(v + dt_b[col]) -> delta bf16 [M][2048]. N=2048
// MODE 3: v + x[row][col] -> out f32 [M][1024]. N=1024
template<int MODE>
__device__ __forceinline__ void gemm_body(const unsigned short* __restrict__ A,
                                          const unsigned short* __restrict__ Bt,
                                          const int M, const int N, const int K,
                                          void* __restrict__ out0,
                                          void* __restrict__ out1,
                                          const float* __restrict__ extra) {
  __shared__ __align__(16) unsigned short sA[2][128 * 64];   // 16 KB per buffer
  __shared__ __align__(16) unsigned short sB[2][128 * 64];
  const int tid = threadIdx.x;
  const int w = tid >> 6, lane = tid & 63;
  // XCD-chunked bijective remap (T1): contiguous tile chunk per XCD
  const int nwg = gridDim.x * gridDim.y;
  const int id  = blockIdx.x + gridDim.x * blockIdx.y;
  const int swz = (id & 7) * (nwg >> 3) + (id >> 3);
  const int bx = swz % gridDim.x, by = swz / gridDim.x;
  const int m0 = by * 128, n0 = bx * 128;
  const int wm = w >> 1, wn = w & 1;
  const int lr = lane & 15, kq = lane >> 4;

  f32x4 acc[4][4] = {};

  // staging: thread t covers rows srow+32i (i=0..3), 16B slot (t&7); source
  // col = 8*((t&7)^(srow&7)) so that linear LDS dest yields the swizzled layout.
  const int srow = tid >> 3;
  const int scol = 8 * ((tid & 7) ^ (srow & 7));
  const unsigned short* gA = A  + (size_t)(m0 + srow) * K + scol;
  const unsigned short* gB = Bt + (size_t)(n0 + srow) * K + scol;

  auto stage = [&](int p, int k0) {
    #pragma unroll
    for (int i = 0; i < 4; ++i) {
      gload16(gA + (size_t)(32 * i) * K + k0, (char*)sA[p] + i * 4096 + tid * 16);
      gload16(gB + (size_t)(32 * i) * K + k0, (char*)sB[p] + i * 4096 + tid * 16);
    }
  };

  // ds_read offsets (elems): logical col byte c = ks*64 + kq*16, phys = c ^ ((lr&7)<<4)
  const int xsw = (lr & 7) << 4;
  const int c0 = ((kq * 16) ^ xsw) >> 1;          // ks = 0
  const int c1 = ((64 + kq * 16) ^ xsw) >> 1;     // ks = 1

  auto compute = [&](int p) {
    const unsigned short* pa = sA[p] + (size_t)(wm * 64 + lr) * 64;
    const unsigned short* pb = sB[p] + (size_t)(wn * 64 + lr) * 64;
    bf16x8 af[4][2], bb[4][2];
    #pragma unroll
    for (int mf = 0; mf < 4; ++mf) {
      af[mf][0] = __builtin_bit_cast(bf16x8, *(const s16x8*)(pa + mf * 16 * 64 + c0));
      af[mf][1] = __builtin_bit_cast(bf16x8, *(const s16x8*)(pa + mf * 16 * 64 + c1));
    }
    #pragma unroll
    for (int nf = 0; nf < 4; ++nf) {
      bb[nf][0] = __builtin_bit_cast(bf16x8, *(const s16x8*)(pb + nf * 16 * 64 + c0));
      bb[nf][1] = __builtin_bit_cast(bf16x8, *(const s16x8*)(pb + nf * 16 * 64 + c1));
    }
    #pragma unroll
    for (int ks = 0; ks < 2; ++ks)
      #pragma unroll
      for (int mf = 0; mf < 4; ++mf)
        #pragma unroll
        for (int nf = 0; nf < 4; ++nf)
          acc[mf][nf] = __builtin_amdgcn_mfma_f32_16x16x32_bf16(af[mf][ks], bb[nf][ks], acc[mf][nf], 0, 0, 0);
  };

  stage(0, 0);
  __syncthreads();
  int p = 0;
  for (int k0 = 64; k0 < K; k0 += 64) {
    stage(p ^ 1, k0);
    compute(p);
    __syncthreads();
    p ^= 1;
  }
  compute(p);

  #pragma unroll
  for (int mf = 0; mf < 4; ++mf) {
    #pragma unroll
    for (int nf = 0; nf < 4; ++nf) {
      #pragma unroll
      for (int r = 0; r < 4; ++r) {
        const int row = m0 + wm*64 + mf*16 + kq*4 + r;
        const int col = n0 + wn*64 + nf*16 + lr;
        const float v = acc[mf][nf][r];
        if constexpr (MODE == 1) {
          if (col < DT_RANK) ((unsigned short*)out0)[(size_t)row * DT_RANK + col] = f2bf(v);
          else if (col < DT_RANK + 2*NSTATE) ((float*)out1)[(size_t)row * (2*NSTATE) + (col - DT_RANK)] = v;
        } else if constexpr (MODE == 2) {
          const float t = v + extra[col];
          const float sp = (t > 30.0f) ? t : __logf(1.0f + __expf(t));
          ((unsigned short*)out0)[(size_t)row * D_INNER + col] = f2bf(sp);
        } else {
          ((float*)out0)[(size_t)row * D_MODEL + col] = v + extra[(size_t)row * D_MODEL + col];
        }
      }
    }
  }
}

__global__ __launch_bounds__(256) void g1_xproj_kernel(const unsigned short* A, const unsigned short* Bt,
                                                       int M, int N, int K, void* o0, void* o1, const float* ex) {
  gemm_body<1>(A, Bt, M, N, K, o0, o1, ex);
}
__global__ __launch_bounds__(256) void g2_dtproj_kernel(const unsigned short* A, const unsigned short* Bt,
                                                        int M, int N, int K, void* o0, void* o1, const float* ex) {
  gemm_body<2>(A, Bt, M, N, K, o0, o1, ex);
}
__global__ __launch_bounds__(256) void g3_outproj_kernel(const unsigned short* A, const unsigned short* Bt,
                                                         int M, int N, int K, void* o0, void* o1, const float* ex) {
  gemm_body<3>(A, Bt, M, N, K, o0, o1, ex);
}

// ---------------- causal depthwise conv (width 4) + bias + SiLU, 8 ch/thread ------
__global__ __launch_bounds__(256) void conv_silu_kernel(const unsigned short* __restrict__ xi_raw,
                                                        const float* __restrict__ cw,
                                                        const float* __restrict__ cb,
                                                        unsigned short* __restrict__ xi) {
  const int t = blockIdx.x * 256 + threadIdx.x;
  const int d8 = (t & 255) * 8;
  const int row = t >> 8;
  const int l = row & (SEQ - 1);

  float acc[8];
  #pragma unroll
  for (int c = 0; c < 8; c += 4) {
    const f32x4 bv = *(const f32x4*)(cb + d8 + c);
    acc[c+0] = bv[0]; acc[c+1] = bv[1]; acc[c+2] = bv[2]; acc[c+3] = bv[3];
  }
  f32x4 wv[8];
  #pragma unroll
  for (int c = 0; c < 8; ++c) wv[c] = ((const f32x4*)cw)[d8 + c];

  #pragma unroll
  for (int tap = 0; tap < 4; ++tap) {
    const int lp = l - 3 + tap;
    if (lp >= 0) {
      const s16x8 v = *(const s16x8*)(xi_raw + (size_t)(row - 3 + tap) * D_INNER + d8);
      #pragma unroll
      for (int c = 0; c < 8; ++c)
        acc[c] += wv[c][tap] * bf2f((unsigned short)v[c]);
    }
  }
  s16x8 o;
  #pragma unroll
  for (int c = 0; c < 8; ++c) {
    const float a = acc[c] / (1.0f + __expf(-acc[c]));
    o[c] = (short)f2bf(a);
  }
  *(s16x8*)(xi + (size_t)row * D_INNER + d8) = o;
}

// ---------------- chunked selective scan ----------------
template<int PASS>
__global__ __launch_bounds__(256) void scan_pass_kernel(const unsigned short* __restrict__ delta,
                                                        const unsigned short* __restrict__ xi,
                                                        const unsigned short* __restrict__ res,
                                                        const float* __restrict__ BC,
                                                        const float* __restrict__ A_log,
                                                        const float* __restrict__ Dv,
                                                        const float* __restrict__ initS,
                                                        float* __restrict__ aprodOut,
                                                        float* __restrict__ sendOut,
                                                        unsigned short* __restrict__ yg) {
  const int tid = threadIdx.x;
  const int db = blockIdx.x & 7;
  const int c  = (blockIdx.x >> 3) & (NC - 1);
  const int b  = blockIdx.x >> 8;
  const int d  = db * 256 + tid;
  const int row0 = b * SEQ + c * CHK;
  const size_t ob = ((size_t)(b * NC + c) * D_INNER + d) * 16;

  float Ac[16];
  #pragma unroll
  for (int q = 0; q < 4; ++q) {
    f32x4 t = ((const f32x4*)(A_log + (size_t)d * 16))[q];
    Ac[q*4+0] = -expf(t[0]); Ac[q*4+1] = -expf(t[1]);
    Ac[q*4+2] = -expf(t[2]); Ac[q*4+3] = -expf(t[3]);
  }
  float s[16];
  float ap[16];
  if constexpr (PASS == 0) {
    #pragma unroll
    for (int n = 0; n < 16; ++n) { s[n] = 0.0f; ap[n] = 1.0f; }
  } else {
    #pragma unroll
    for (int q = 0; q < 4; ++q)
      ((f32x4*)s)[q] = ((const f32x4*)(initS + ob))[q];
  }
  float Dd = 0.0f;
  if constexpr (PASS == 1) Dd = Dv[d];

  __shared__ float bcbuf[2][8][32];
  auto stageg = [&](int g, int p) {
    bcbuf[p][tid >> 5][tid & 31] = BC[(size_t)(row0 + g * 8) * 32 + tid];
  };
  stageg(0, 0);

  for (int g = 0; g < NGRP; ++g) {
    unsigned short dl[8], uu[8], rr[8];
    #pragma unroll
    for (int j = 0; j < 8; ++j) {
      const size_t row = (size_t)(row0 + g * 8 + j) * D_INNER + d;
      dl[j] = delta[row];
      uu[j] = xi[row];
      if constexpr (PASS == 1) rr[j] = res[row];
    }
    __syncthreads();
    if (g + 1 < NGRP) stageg(g + 1, (g + 1) & 1);

    #pragma unroll
    for (int j = 0; j < 8; ++j) {
      const float dlt = bf2f(dl[j]);
      const float u   = bf2f(uu[j]);
      const float dlu = dlt * u;
      float bc[32];
      #pragma unroll
      for (int q = 0; q < (PASS ? 8 : 4); ++q)
        ((f32x4*)bc)[q] = ((const f32x4*)(&bcbuf[g & 1][j][0]))[q];
      #pragma unroll
      for (int n = 0; n < 16; ++n) {
        const float dA = __expf(dlt * Ac[n]);
        s[n] = dA * s[n] + dlu * bc[n];
        if constexpr (PASS == 0) ap[n] *= dA;
      }
      if constexpr (PASS == 1) {
        float y = 0.0f;
        #pragma unroll
        for (int n = 0; n < 16; ++n) y += s[n] * bc[16 + n];
        const float r = bf2f(rr[j]);
        const float o = (y + u * Dd) * (r / (1.0f + __expf(-r)));
        yg[(size_t)(row0 + g * 8 + j) * D_INNER + d] = f2bf(o);
      }
    }
  }

  if constexpr (PASS == 0) {
    #pragma unroll
    for (int q = 0; q < 4; ++q) {
      ((f32x4*)(aprodOut + ob))[q] = ((f32x4*)ap)[q];
      ((f32x4*)(sendOut + ob))[q]  = ((f32x4*)s)[q];
    }
  }
}

// ---------------- combine chunk summaries ----------------
__global__ __launch_bounds__(256) void scan_combine_kernel(const float* __restrict__ aprod,
                                                           const float* __restrict__ send,
                                                           float* __restrict__ initS) {
  const int t = blockIdx.x * 256 + threadIdx.x;
  const int b = t >> 13;
  const int rq = t & 8191;
  f32x4 carry = {0.0f, 0.0f, 0.0f, 0.0f};
  #pragma unroll
  for (int c = 0; c < NC; ++c) {
    const size_t idx = (size_t)(b * NC + c) * 8192 + rq;
    ((f32x4*)initS)[idx] = carry;
    const f32x4 a = ((const f32x4*)aprod)[idx];
    const f32x4 e = ((const f32x4*)send)[idx];
    carry = a * carry + e;
  }
}

// ---------------- launcher ----------------
extern "C" void kernel_launch(void* const* d_in, const int* in_sizes, int n_in,
                              void* d_out, int out_size, void* d_ws, size_t ws_size,
                              hipStream_t stream) {
  const float* x        = (const float*)d_in[0];
  const float* in_proj  = (const float*)d_in[1];
  const float* conv_w   = (const float*)d_in[2];
  const float* conv_b   = (const float*)d_in[3];
  const float* x_proj   = (const float*)d_in[4];
  const float* dt_proj  = (const float*)d_in[5];
  const float* dt_b     = (const float*)d_in[6];
  const float* A_log    = (const float*)d_in[7];
  const float* Dv       = (const float*)d_in[8];
  const float* out_proj = (const float*)d_in[9];
  const float* norm_w   = (const float*)d_in[10];

  char* ws = (char*)d_ws;
  size_t off = 0;
  auto alloc = [&](size_t bytes) {
    char* p = ws + off; off += (bytes + 255) & ~(size_t)255; return p;
  };
  unsigned short* xn     = (unsigned short*)alloc((size_t)NTOK * D_MODEL * 2);   // 8 MB (reused as initS)
  unsigned short* W1t    = (unsigned short*)alloc((size_t)(2 * D_INNER) * D_MODEL * 2);
  unsigned short* xi_raw = (unsigned short*)alloc((size_t)NTOK * D_INNER * 2);   // 16 MB (reused: aprod+send)
  unsigned short* resb   = (unsigned short*)alloc((size_t)NTOK * D_INNER * 2);
  unsigned short* xi     = (unsigned short*)alloc((size_t)NTOK * D_INNER * 2);
  unsigned short* W2t    = (unsigned short*)alloc((size_t)128 * D_INNER * 2);
  unsigned short* dr     = (unsigned short*)alloc((size_t)NTOK * DT_RANK * 2);
  float*          BC     = (float*)alloc((size_t)NTOK * 32 * 4);
  unsigned short* W3t    = (unsigned short*)alloc((size_t)D_INNER * DT_RANK * 2);
  unsigned short* dlt    = (unsigned short*)alloc((size_t)NTOK * D_INNER * 2);
  unsigned short* ygb    = (unsigned short*)alloc((size_t)NTOK * D_INNER * 2);
  unsigned short* W4t    = (unsigned short*)alloc((size_t)D_MODEL * D_INNER * 2);

  float* aprod = (float*)xi_raw;
  float* send  = (float*)((char*)xi_raw + 8388608);
  float* initS = (float*)xn;

  prep_fused_kernel<<<10624, 256, 0, stream>>>(x, norm_w, xn,
                                               in_proj, W1t, x_proj, W2t,
                                               dt_proj, W3t, out_proj, W4t);

  g0_inproj_kernel<<<dim3(4096/256, 4096/256), 512, 0, stream>>>(xn, W1t, xi_raw, resb);
  conv_silu_kernel<<<NTOK, 256, 0, stream>>>(xi_raw, conv_w, conv_b, xi);
  g1_xproj_kernel<<<dim3(1, 4096/128), 256, 0, stream>>>(xi, W2t, NTOK, 128, 2048, dr, BC, nullptr);
  g2_dtproj_kernel<<<dim3(2048/128, 4096/128), 256, 0, stream>>>(dr, W3t, NTOK, 2048, 64, dlt, nullptr, dt_b);

  scan_pass_kernel<0><<<NBATCH * NC * (D_INNER/256), 256, 0, stream>>>(
      dlt, xi, nullptr, BC, A_log, nullptr, nullptr, aprod, send, nullptr);
  scan_combine_kernel<<<64, 256, 0, stream>>>(aprod, send, initS);
  scan_pass_kernel<1><<<NBATCH * NC * (D_INNER/256), 256, 0, stream>>>(
      dlt, xi, resb, BC, A_log, Dv, initS, nullptr, nullptr, ygb);

  g3_outproj_kernel<<<dim3(1024/128, 4096/128), 256, 0, stream>>>(ygb, W4t, NTOK, 1024, 2048, d_out, nullptr, x);
}